// Round 3
// baseline (18556.230 us; speedup 1.0000x reference)
//
#include <hip/hip_runtime.h>
#include <hip/hip_fp16.h>

typedef unsigned short u16;
typedef unsigned int u32;
typedef unsigned long long u64;

#define NT 512      // time steps
#define NB 256      // batch
#define NH 1024     // hidden
#define NE 128      // emb dim
#define NHE 1152    // H+E
#define NL 17       // labels
#define MT 4        // batch tiles (64 rows each)
#define JTILES 32   // hidden-col tiles (32 cols each)
#define XKC 36      // K-chunks (32 wide) for x part
#define HKC 32      // K-chunks for h part
#define KCT 68      // XKC + HKC
#define NBLK 128    // MT * JTILES
#define THREADS 256

typedef __attribute__((ext_vector_type(8))) _Float16 half8;
typedef __attribute__((ext_vector_type(4))) float f32x4;
typedef __attribute__((ext_vector_type(4))) u32 u32x4;   // nontemporal-compatible 16B vector

// ---- workspace layout (bytes) ----
#define WS_CNT     0ull
#define WS_HBUF    4096ull                   // 2 * 4 * 32 * 4096 = 1,048,576
#define WS_WPACK   1052672ull                // 32*68*6*1024     = 13,369,344
#define WS_WOPACK  14422016ull               // 32*2*1024        = 65,536
#define WS_XPACK   14487552ull               // 4*512*36*4096    = 301,989,888
#define WS_TOTAL   316477440ull

__device__ __forceinline__ u16 f2h(float f) {
  __half h = __float2half(f);
  return __builtin_bit_cast(u16, h);
}
__device__ __forceinline__ float h2f(u16 u) {
  return __half2float(__builtin_bit_cast(__half, u));
}
__device__ __forceinline__ uint4 pack8h(const u16* o) {
  uint4 v;
  v.x = (u32)o[0] | ((u32)o[1] << 16);
  v.y = (u32)o[2] | ((u32)o[3] << 16);
  v.z = (u32)o[4] | ((u32)o[5] << 16);
  v.w = (u32)o[6] | ((u32)o[7] << 16);
  return v;
}

// ---------------- zero counters + h parity-0 ----------------
__global__ void zero_ws(uint4* p) {
  int idx = blockIdx.x * 256 + threadIdx.x;
  if (idx < 33024) {
    uint4 z; z.x = 0; z.y = 0; z.z = 0; z.w = 0;
    p[idx] = z;
  }
}

// ---------------- pack weights into B-fragment order ----------------
__global__ void pack_w(const float* __restrict__ Wih, const float* __restrict__ Whh,
                       const float* __restrict__ Wout, u16* __restrict__ wpack,
                       u16* __restrict__ wopack) {
  int idx = blockIdx.x * 256 + threadIdx.x;
  const int WUNITS = JTILES * KCT * 3 * 2 * 64;   // 835584
  if (idx < WUNITS) {
    int l = idx & 63;
    int r = idx >> 6;
    int ni = r & 1; r >>= 1;
    int g = r % 3;  r /= 3;
    int kc = r % KCT; r /= KCT;
    int jt = r;
    int row = g * NH + jt * 32 + ni * 16 + (l & 15);
    int kk = (l >> 4) * 8;
    const float* src = (kc < XKC) ? (Wih + (size_t)row * NHE + kc * 32 + kk)
                                  : (Whh + (size_t)row * NH + (kc - XKC) * 32 + kk);
    u16 o[8];
#pragma unroll
    for (int e = 0; e < 8; ++e) o[e] = f2h(src[e]);
    ((uint4*)wpack)[idx] = pack8h(o);
  } else if (idx < WUNITS + HKC * 2 * 64) {
    int j = idx - WUNITS;
    int l = j & 63; j >>= 6;
    int ni = j & 1; int kc = j >> 1;
    int col = (l & 15) + 16 * ni;
    int kk = kc * 32 + (l >> 4) * 8;
    u16 o[8];
#pragma unroll
    for (int e = 0; e < 8; ++e)
      o[e] = (col < NL) ? f2h(Wout[(size_t)col * NH + kk + e]) : (u16)0;
    ((uint4*)wopack)[idx - WUNITS] = pack8h(o);
  }
}

// ---------------- pack x = [seg | emb(prev_label)] into A-fragment order ----------------
__global__ void pack_x(const float* __restrict__ seg, const int* __restrict__ labels,
                       const float* __restrict__ emb, u16* __restrict__ xpack) {
  __shared__ float ls[64][33];
  __shared__ int lbl[64];
  const int bid = blockIdx.x;
  const int t = bid & (NT - 1);
  const int m = bid >> 9;
  const int tid = threadIdx.x;
  u16* outb = xpack + (size_t)(m * NT + t) * (XKC * 4 * 64 * 8);
  const int r = tid >> 2, qq = tid & 3;
  const int sub = tid >> 6, l = tid & 63;
  const int row = sub * 16 + (l & 15), c0 = (l >> 4) * 8;

  for (int kc = 0; kc < 32; ++kc) {
    const float* s = seg + ((size_t)(m * 64 + r) * NT + t) * NH + kc * 32 + qq * 8;
    float4 a = ((const float4*)s)[0];
    float4 b2 = ((const float4*)s)[1];
    ls[r][qq * 8 + 0] = a.x;  ls[r][qq * 8 + 1] = a.y;
    ls[r][qq * 8 + 2] = a.z;  ls[r][qq * 8 + 3] = a.w;
    ls[r][qq * 8 + 4] = b2.x; ls[r][qq * 8 + 5] = b2.y;
    ls[r][qq * 8 + 6] = b2.z; ls[r][qq * 8 + 7] = b2.w;
    __syncthreads();
    u16 o[8];
#pragma unroll
    for (int e = 0; e < 8; ++e) o[e] = f2h(ls[row][c0 + e]);
    ((uint4*)outb)[(kc * 4 + sub) * 64 + l] = pack8h(o);
    __syncthreads();
  }
  if (tid < 64)
    lbl[tid] = (t == 0) ? NL : labels[(size_t)(m * 64 + tid) * NT + (t - 1)];
  __syncthreads();
  for (int u = tid; u < 1024; u += 256) {
    int ll = u & 63; int sb = (u >> 6) & 3; int kc = 32 + (u >> 8);
    int rw = sb * 16 + (ll & 15);
    int kk = (kc - 32) * 32 + ((ll >> 4) * 8);
    const float* s = emb + (size_t)lbl[rw] * NE + kk;
    float4 a = ((const float4*)s)[0];
    float4 b2 = ((const float4*)s)[1];
    u16 o[8];
    o[0] = f2h(a.x); o[1] = f2h(a.y); o[2] = f2h(a.z); o[3] = f2h(a.w);
    o[4] = f2h(b2.x); o[5] = f2h(b2.y); o[6] = f2h(b2.z); o[7] = f2h(b2.w);
    ((uint4*)outb)[(kc * 4 + sb) * 64 + ll] = pack8h(o);
  }
}

// ---------------- persistent GRU kernel ----------------
#define MFMA16(a, b, c) __builtin_amdgcn_mfma_f32_16x16x32_f16((a), (b), (c), 0, 0, 0)

// x A-frags: nontemporal (read once; don't evict resident weights)
#define LOADX(i, BA, BB) do { \
  const int kc_ = w * 9 + (i); \
  const size_t xu_ = xbase_u + (size_t)(kc_ * 4) * 64 + l; \
  BA[0] = __builtin_nontemporal_load(&xp[xu_]); \
  BA[1] = __builtin_nontemporal_load(&xp[xu_ + 64]); \
  BA[2] = __builtin_nontemporal_load(&xp[xu_ + 128]); \
  BA[3] = __builtin_nontemporal_load(&xp[xu_ + 192]); \
  const size_t wu_ = wbase_u + (size_t)(kc_ * 6) * 64 + l; \
  BB[0] = wp[wu_];       BB[1] = wp[wu_ + 64]; \
  BB[2] = wp[wu_ + 128]; BB[3] = wp[wu_ + 192]; \
  BB[4] = wp[wu_ + 256]; BB[5] = wp[wu_ + 320]; \
} while (0)

#define MFMAX(BA, BB) do { \
  _Pragma("unroll") \
  for (int s_ = 0; s_ < 4; ++s_) { \
    half8 a_ = __builtin_bit_cast(half8, BA[s_]); \
    _Pragma("unroll") \
    for (int n_ = 0; n_ < 2; ++n_) { \
      aR[s_][n_]  = MFMA16(a_, __builtin_bit_cast(half8, BB[n_]),     aR[s_][n_]); \
      aZ[s_][n_]  = MFMA16(a_, __builtin_bit_cast(half8, BB[2 + n_]), aZ[s_][n_]); \
      aXN[s_][n_] = MFMA16(a_, __builtin_bit_cast(half8, BB[4 + n_]), aXN[s_][n_]); \
    } \
  } \
} while (0)

#define LOADHB(i, BB) do { \
  const int kc_ = XKC + w * 8 + (i); \
  const size_t wu_ = wbase_u + (size_t)(kc_ * 6) * 64 + l; \
  BB[0] = wp[wu_];       BB[1] = wp[wu_ + 64]; \
  BB[2] = wp[wu_ + 128]; BB[3] = wp[wu_ + 192]; \
  BB[4] = wp[wu_ + 256]; BB[5] = wp[wu_ + 320]; \
} while (0)

#define HA2FRAG(ci, s_, a_) \
  uint4 av_; \
  av_.x = (u32)hA[ci][s_][0]; av_.y = (u32)(hA[ci][s_][0] >> 32); \
  av_.z = (u32)hA[ci][s_][1]; av_.w = (u32)(hA[ci][s_][1] >> 32); \
  half8 a_ = __builtin_bit_cast(half8, av_);

#define MFMAH(ci, BB) do { \
  _Pragma("unroll") \
  for (int s_ = 0; s_ < 4; ++s_) { \
    HA2FRAG(ci, s_, a_) \
    _Pragma("unroll") \
    for (int n_ = 0; n_ < 2; ++n_) { \
      aR[s_][n_]  = MFMA16(a_, __builtin_bit_cast(half8, BB[n_]),     aR[s_][n_]); \
      aZ[s_][n_]  = MFMA16(a_, __builtin_bit_cast(half8, BB[2 + n_]), aZ[s_][n_]); \
      aHN[s_][n_] = MFMA16(a_, __builtin_bit_cast(half8, BB[4 + n_]), aHN[s_][n_]); \
    } \
  } \
} while (0)

#define WRSLICE(gi, ACC) do { \
  u16 o_[8]; \
  _Pragma("unroll") for (int n_ = 0; n_ < 2; ++n_) \
  _Pragma("unroll") for (int r_ = 0; r_ < 4; ++r_) o_[n_ * 4 + r_] = f2h(ACC[tw][n_][r_]); \
  redbuf[((tw * 3 + slot) * 4 + (gi)) * 64 + l] = pack8h(o_); \
} while (0)

#define RDSLICE(gi, SACC) do { \
  uint4 v_ = redbuf[((w * 3 + slot) * 4 + (gi)) * 64 + l]; \
  u32 vv_[4] = {v_.x, v_.y, v_.z, v_.w}; \
  _Pragma("unroll") for (int n_ = 0; n_ < 2; ++n_) \
  _Pragma("unroll") for (int r_ = 0; r_ < 4; ++r_) { \
    const int ix_ = n_ * 4 + r_; \
    u16 hu_ = (u16)(vv_[ix_ >> 1] >> ((ix_ & 1) * 16)); \
    SACC[n_][r_] += h2f(hu_); \
  } \
} while (0)

// logits partial from live hA + wopack; aL must be declared by caller
#define MFMAL(ci, OO) do { \
  _Pragma("unroll") \
  for (int s_ = 0; s_ < 4; ++s_) { \
    HA2FRAG(ci, s_, a_) \
    aL[s_][0] = MFMA16(a_, __builtin_bit_cast(half8, OO[0]), aL[s_][0]); \
    aL[s_][1] = MFMA16(a_, __builtin_bit_cast(half8, OO[1]), aL[s_][1]); \
  } \
} while (0)

__global__ __launch_bounds__(THREADS, 1)
void gru_persist(const u16* __restrict__ xpack, const u16* __restrict__ wpack,
                 const u16* __restrict__ wopack,
                 const float* __restrict__ bih, const float* __restrict__ bhh,
                 const float* __restrict__ bout,
                 u64* __restrict__ hbuf, u32* __restrict__ counters,
                 float* __restrict__ out) {
  __shared__ uint4 redbuf[4 * 3 * 4 * 64];   // 48KB exchange
  __shared__ u16 hbf[64 * 40];               // 5KB fp16 bounce for h fragment write

  const int bid = blockIdx.x;
  const int xcd = bid & 7;
  const int q = bid >> 3;
  const int m = q & 3;
  const int jslot = q >> 2;
  const int jt = jslot * 8 + xcd;            // same-jt blocks co-located per XCD
  const int tid = threadIdx.x;
  const int w = tid >> 6, l = tid & 63;
  const int l15 = l & 15, l4 = l >> 4;

  const u32x4* xp = (const u32x4*)xpack;
  const uint4* wp = (const uint4*)wpack;
  const uint4* wo = (const uint4*)wopack;
  f32x4* redv = (f32x4*)redbuf;
  u32* cnt = counters + m * 16;
  const size_t wbase_u = (size_t)jt * (KCT * 6 * 64);

  float br[2], bz[2], bxn[2], bhn[2];
#pragma unroll
  for (int ni = 0; ni < 2; ++ni) {
    int col = jt * 32 + ni * 16 + l15;
    br[ni] = bih[col] + bhh[col];
    bz[ni] = bih[NH + col] + bhh[NH + col];
    bxn[ni] = bih[2 * NH + col];
    bhn[ni] = bhh[2 * NH + col];
  }
  float hold[2][4] = {{0.f, 0.f, 0.f, 0.f}, {0.f, 0.f, 0.f, 0.f}};
  const f32x4 z4 = {0.f, 0.f, 0.f, 0.f};

  for (int t = 0; t < NT; ++t) {
    const int par = t & 1;
    const size_t xbase_u = (size_t)(m * NT + t) * (XKC * 4 * 64);
    const bool duty = (jt == (t & 31));      // rotating logits duty
    f32x4 aR[4][2], aZ[4][2], aXN[4][2], aHN[4][2];
#pragma unroll
    for (int s_ = 0; s_ < 4; ++s_)
#pragma unroll
      for (int n_ = 0; n_ < 2; ++n_) {
        aR[s_][n_] = z4; aZ[s_][n_] = z4; aXN[s_][n_] = z4; aHN[s_][n_] = z4;
      }

    // ---- x phase (independent work; overlaps other blocks' tails) ----
    {
      u32x4 xA0[4], xA1[4];
      uint4 xB0[6], xB1[6];
      LOADX(0, xA0, xB0);
#pragma unroll
      for (int i = 0; i < 9; ++i) {
        if ((i & 1) == 0) { if (i < 8) LOADX(i + 1, xA1, xB1); MFMAX(xA0, xB0); }
        else              { if (i < 8) LOADX(i + 1, xA0, xB0); MFMAX(xA1, xB1); }
      }
    }

    // ---- wait for group's h(t): all lanes spin, acquire ----
    {
      const u32 target = 32u * (u32)t;
      while (__hip_atomic_load(cnt, __ATOMIC_ACQUIRE, __HIP_MEMORY_SCOPE_AGENT) < target)
        __builtin_amdgcn_s_sleep(1);
    }

    // ---- h phase: preload all A-frags (one LLC latency), stream B dbuf ----
    u64 hA[8][4][2];
    {
      u64* hb_ = hbuf + (size_t)(par * MT + m) * (HKC * 4 * 64 * 2);
#pragma unroll
      for (int c_ = 0; c_ < 8; ++c_)
#pragma unroll
        for (int s_ = 0; s_ < 4; ++s_) {
          const size_t o_ = ((size_t)((w * 8 + c_) * 4 + s_) * 64 + l) * 2;
          hA[c_][s_][0] = __hip_atomic_load(hb_ + o_, __ATOMIC_RELAXED, __HIP_MEMORY_SCOPE_AGENT);
          hA[c_][s_][1] = __hip_atomic_load(hb_ + o_ + 1, __ATOMIC_RELAXED, __HIP_MEMORY_SCOPE_AGENT);
        }
    }
    {
      uint4 hB0[6], hB1[6];
      LOADHB(0, hB0);
#pragma unroll
      for (int i = 0; i < 8; ++i) {
        if ((i & 1) == 0) { if (i < 7) LOADHB(i + 1, hB1); MFMAH(i, hB0); }
        else              { if (i < 7) LOADHB(i + 1, hB0); MFMAH(i, hB1); }
      }
    }

    // ---- cross-wave k-reduction (f16 exchange), wave w keeps row subtile w ----
    f32x4 sR[2], sZ[2], sXN[2], sHN[2];
#pragma unroll
    for (int tw = 0; tw < 4; ++tw) {
      if (tw == w) {
        sR[0] = aR[tw][0]; sR[1] = aR[tw][1];
        sZ[0] = aZ[tw][0]; sZ[1] = aZ[tw][1];
        sXN[0] = aXN[tw][0]; sXN[1] = aXN[tw][1];
        sHN[0] = aHN[tw][0]; sHN[1] = aHN[tw][1];
      } else {
        const int slot = (w > tw) ? (w - 1) : w;
        WRSLICE(0, aR); WRSLICE(1, aZ); WRSLICE(2, aXN); WRSLICE(3, aHN);
      }
    }
    __syncthreads();
#pragma unroll
    for (int slot = 0; slot < 3; ++slot) {
      RDSLICE(0, sR); RDSLICE(1, sZ); RDSLICE(2, sXN); RDSLICE(3, sHN);
    }

    // ---- gate math (fp32 carried state in registers) ----
#pragma unroll
    for (int ni = 0; ni < 2; ++ni) {
      const int col = l15 + 16 * ni;
#pragma unroll
      for (int rg = 0; rg < 4; ++rg) {
        float R = sR[ni][rg] + br[ni];
        float Z = sZ[ni][rg] + bz[ni];
        float XNv = sXN[ni][rg] + bxn[ni];
        float HNv = sHN[ni][rg] + bhn[ni];
        float r_ = 1.f / (1.f + __expf(-R));
        float z_ = 1.f / (1.f + __expf(-Z));
        float pre = XNv + r_ * HNv;
        float e2 = __expf(2.f * pre);
        float n_ = 1.f - 2.f / (e2 + 1.f);
        float hn_ = (1.f - z_) * n_ + z_ * hold[ni][rg];
        hold[ni][rg] = hn_;
        const int row = w * 16 + l4 * 4 + rg;
        hbf[row * 40 + col] = f2h(hn_);
      }
    }
    __syncthreads();

    // ---- write h(t+1) fragment chunk (kc = jt) to global ----
    {
      const int row = w * 16 + l15;
      const uint4 hv = *(const uint4*)&hbf[(size_t)row * 40 + l4 * 8];
      u64 lo = ((u64)hv.y << 32) | (u64)hv.x;
      u64 hi = ((u64)hv.w << 32) | (u64)hv.z;
      u64* dst = hbuf + (size_t)((par ^ 1) * MT + m) * (HKC * 4 * 64 * 2)
                      + ((size_t)(jt * 4 + w) * 64 + l) * 2;
      __hip_atomic_store(dst, lo, __ATOMIC_RELAXED, __HIP_MEMORY_SCOPE_AGENT);
      __hip_atomic_store(dst + 1, hi, __ATOMIC_RELAXED, __HIP_MEMORY_SCOPE_AGENT);
    }
    __syncthreads();   // drains all waves' stores before the flag
    if (tid == 0)
      __hip_atomic_fetch_add(cnt, 1u, __ATOMIC_RELEASE, __HIP_MEMORY_SCOPE_AGENT);

    // ---- rotating duty block: logits[:, t-1] from live hA (post-signal slack) ----
    if (duty && t > 0) {
      f32x4 aL[4][2];
#pragma unroll
      for (int s_ = 0; s_ < 4; ++s_) { aL[s_][0] = z4; aL[s_][1] = z4; }
      uint4 O0[2], O1[2];
      O0[0] = wo[(size_t)((w * 8) * 2) * 64 + l];
      O0[1] = wo[(size_t)((w * 8) * 2 + 1) * 64 + l];
#pragma unroll
      for (int i = 0; i < 8; ++i) {
        if ((i & 1) == 0) {
          if (i < 7) { O1[0] = wo[(size_t)((w * 8 + i + 1) * 2) * 64 + l];
                       O1[1] = wo[(size_t)((w * 8 + i + 1) * 2 + 1) * 64 + l]; }
          MFMAL(i, O0);
        } else {
          if (i < 7) { O0[0] = wo[(size_t)((w * 8 + i + 1) * 2) * 64 + l];
                       O0[1] = wo[(size_t)((w * 8 + i + 1) * 2 + 1) * 64 + l]; }
          MFMAL(i, O1);
        }
      }
      f32x4 sL[2];
#pragma unroll
      for (int tw = 0; tw < 4; ++tw) {
        if (tw == w) { sL[0] = aL[tw][0]; sL[1] = aL[tw][1]; }
        else {
          const int slot = (w > tw) ? (w - 1) : w;
          redv[((tw * 3 + slot) * 2 + 0) * 64 + l] = aL[tw][0];
          redv[((tw * 3 + slot) * 2 + 1) * 64 + l] = aL[tw][1];
        }
      }
      __syncthreads();
#pragma unroll
      for (int slot = 0; slot < 3; ++slot) {
        sL[0] += redv[((w * 3 + slot) * 2 + 0) * 64 + l];
        sL[1] += redv[((w * 3 + slot) * 2 + 1) * 64 + l];
      }
#pragma unroll
      for (int ni = 0; ni < 2; ++ni) {
        const int col = l15 + 16 * ni;
        if (col < NL) {
#pragma unroll
          for (int rg = 0; rg < 4; ++rg) {
            const int row = w * 16 + l4 * 4 + rg;
            const size_t b_ = (size_t)m * 64 + row;
            out[(b_ * NT + (t - 1)) * NL + col] = sL[ni][rg] + bout[col];
          }
        }
      }
      __syncthreads();
    }
  }

  // ---- epilogue: logits[:, 511] from h_512 (parity 0), blocks jt==0 ----
  if (jt == 0) {
    {
      while (__hip_atomic_load(cnt, __ATOMIC_ACQUIRE, __HIP_MEMORY_SCOPE_AGENT) < 32u * 512u)
        __builtin_amdgcn_s_sleep(1);
    }
    u64 hA[8][4][2];
    u64* hb_ = hbuf + (size_t)(0 * MT + m) * (HKC * 4 * 64 * 2);
#pragma unroll
    for (int c_ = 0; c_ < 8; ++c_)
#pragma unroll
      for (int s_ = 0; s_ < 4; ++s_) {
        const size_t o_ = ((size_t)((w * 8 + c_) * 4 + s_) * 64 + l) * 2;
        hA[c_][s_][0] = __hip_atomic_load(hb_ + o_, __ATOMIC_RELAXED, __HIP_MEMORY_SCOPE_AGENT);
        hA[c_][s_][1] = __hip_atomic_load(hb_ + o_ + 1, __ATOMIC_RELAXED, __HIP_MEMORY_SCOPE_AGENT);
      }
    f32x4 aL[4][2];
    const f32x4 z4b = {0.f, 0.f, 0.f, 0.f};
#pragma unroll
    for (int s_ = 0; s_ < 4; ++s_) { aL[s_][0] = z4b; aL[s_][1] = z4b; }
#pragma unroll
    for (int c_ = 0; c_ < 8; ++c_) {
      uint4 O0[2];
      O0[0] = wo[(size_t)((w * 8 + c_) * 2) * 64 + l];
      O0[1] = wo[(size_t)((w * 8 + c_) * 2 + 1) * 64 + l];
      MFMAL(c_, O0);
    }
    f32x4 sL[2];
#pragma unroll
    for (int tw = 0; tw < 4; ++tw) {
      if (tw == w) { sL[0] = aL[tw][0]; sL[1] = aL[tw][1]; }
      else {
        const int slot = (w > tw) ? (w - 1) : w;
        redv[((tw * 3 + slot) * 2 + 0) * 64 + l] = aL[tw][0];
        redv[((tw * 3 + slot) * 2 + 1) * 64 + l] = aL[tw][1];
      }
    }
    __syncthreads();
#pragma unroll
    for (int slot = 0; slot < 3; ++slot) {
      sL[0] += redv[((w * 3 + slot) * 2 + 0) * 64 + l];
      sL[1] += redv[((w * 3 + slot) * 2 + 1) * 64 + l];
    }
#pragma unroll
    for (int ni = 0; ni < 2; ++ni) {
      const int col = l15 + 16 * ni;
      if (col < NL) {
#pragma unroll
        for (int rg = 0; rg < 4; ++rg) {
          const int row = w * 16 + l4 * 4 + rg;
          const size_t b_ = (size_t)m * 64 + row;
          out[(b_ * NT + 511) * NL + col] = sL[ni][rg] + bout[col];
        }
      }
    }
  }
}

extern "C" void kernel_launch(void* const* d_in, const int* in_sizes, int n_in,
                              void* d_out, int out_size, void* d_ws, size_t ws_size,
                              hipStream_t stream) {
  (void)in_sizes; (void)n_in; (void)out_size;
  const float* seg   = (const float*)d_in[0];
  const int*   labels= (const int*)d_in[1];
  const float* emb   = (const float*)d_in[2];
  const float* Wih   = (const float*)d_in[3];
  const float* Whh   = (const float*)d_in[4];
  const float* bih   = (const float*)d_in[5];
  const float* bhh   = (const float*)d_in[6];
  const float* Wout  = (const float*)d_in[7];
  const float* bout  = (const float*)d_in[8];
  float* out = (float*)d_out;
  char* ws = (char*)d_ws;
  if (ws_size < WS_TOTAL) return;

  zero_ws<<<129, 256, 0, stream>>>((uint4*)(ws + WS_CNT));
  pack_w<<<3280, 256, 0, stream>>>(Wih, Whh, Wout,
                                   (u16*)(ws + WS_WPACK), (u16*)(ws + WS_WOPACK));
  pack_x<<<2048, 256, 0, stream>>>(seg, labels, emb, (u16*)(ws + WS_XPACK));
  gru_persist<<<NBLK, THREADS, 0, stream>>>(
      (const u16*)(ws + WS_XPACK), (const u16*)(ws + WS_WPACK),
      (const u16*)(ws + WS_WOPACK), bih, bhh, bout,
      (u64*)(ws + WS_HBUF), (u32*)(ws + WS_CNT), out);
}

// Round 4
// 15735.892 us; speedup vs baseline: 1.1792x; 1.1792x over previous
//
#include <hip/hip_runtime.h>
#include <hip/hip_fp16.h>

typedef unsigned short u16;
typedef unsigned int u32;
typedef unsigned long long u64;

#define NT 512      // time steps
#define NB 256      // batch
#define NH 1024     // hidden
#define NE 128      // emb dim
#define NHE 1152    // H+E
#define NL 17       // labels
#define MT 8        // batch groups (32 rows each)
#define JTILES 32   // hidden-col tiles (32 cols each)
#define XKC 36      // K-chunks (32 wide) for x part
#define HKC 32      // K-chunks for h part
#define KCT 68      // XKC + HKC
#define NBLK 256    // MT * JTILES
#define THREADS 256

typedef __attribute__((ext_vector_type(8))) _Float16 half8;
typedef __attribute__((ext_vector_type(4))) float f32x4;

// ---- workspace layout (bytes) ----
// hbuf: 2 parity * 8 groups * (32kc * 2sub * 64l * 16B) = 2*8*65536 = 1,048,576
#define WS_CNT     0ull
#define WS_HBUF    4096ull
#define WS_WPACK   1052672ull                // 32*68*6*1024     = 13,369,344
#define WS_WOPACK  14422016ull               // 32*2*1024        = 65,536
#define WS_XPACK   14487552ull               // 8*512*36*2*64*16 = 301,989,888
#define WS_TOTAL   316477440ull

#define HB_U64_PER (HKC * 2 * 64 * 2)        // 8192 u64 per (par,m)

__device__ __forceinline__ u16 f2h(float f) {
  __half h = __float2half(f);
  return __builtin_bit_cast(u16, h);
}
__device__ __forceinline__ uint4 pack8h(const u16* o) {
  uint4 v;
  v.x = (u32)o[0] | ((u32)o[1] << 16);
  v.y = (u32)o[2] | ((u32)o[3] << 16);
  v.z = (u32)o[4] | ((u32)o[5] << 16);
  v.w = (u32)o[6] | ((u32)o[7] << 16);
  return v;
}

// ---------------- zero counters + h parity-0 ----------------
__global__ void zero_ws(uint4* p) {
  // cnt 4096B + parity-0 hbuf 524288B = 33024 uint4
  int idx = blockIdx.x * 256 + threadIdx.x;
  if (idx < 33024) {
    uint4 z; z.x = 0; z.y = 0; z.z = 0; z.w = 0;
    p[idx] = z;
  }
}

// ---------------- pack weights into B-fragment order ----------------
// wpack unit: (((jt*KCT+kc)*3+g)*2+ni)*64 + l  (16B each)
// B-frag: col = jt*32 + ni*16 + (l&15), k = kc*32 + (l>>4)*8 + e
__global__ void pack_w(const float* __restrict__ Wih, const float* __restrict__ Whh,
                       const float* __restrict__ Wout, u16* __restrict__ wpack,
                       u16* __restrict__ wopack) {
  int idx = blockIdx.x * 256 + threadIdx.x;
  const int WUNITS = JTILES * KCT * 3 * 2 * 64;   // 835584
  if (idx < WUNITS) {
    int l = idx & 63;
    int r = idx >> 6;
    int ni = r & 1; r >>= 1;
    int g = r % 3;  r /= 3;
    int kc = r % KCT; r /= KCT;
    int jt = r;
    int row = g * NH + jt * 32 + ni * 16 + (l & 15);
    int kk = (l >> 4) * 8;
    const float* src = (kc < XKC) ? (Wih + (size_t)row * NHE + kc * 32 + kk)
                                  : (Whh + (size_t)row * NH + (kc - XKC) * 32 + kk);
    u16 o[8];
#pragma unroll
    for (int e = 0; e < 8; ++e) o[e] = f2h(src[e]);
    ((uint4*)wpack)[idx] = pack8h(o);
  } else if (idx < WUNITS + HKC * 2 * 64) {
    int j = idx - WUNITS;
    int l = j & 63; j >>= 6;
    int ni = j & 1; int kc = j >> 1;
    int col = (l & 15) + 16 * ni;
    int kk = kc * 32 + (l >> 4) * 8;
    u16 o[8];
#pragma unroll
    for (int e = 0; e < 8; ++e)
      o[e] = (col < NL) ? f2h(Wout[(size_t)col * NH + kk + e]) : (u16)0;
    ((uint4*)wopack)[idx - WUNITS] = pack8h(o);
  }
}

// ---------------- pack x = [seg | emb(prev)] into A-fragment order ----------------
// xpack unit per (m,t): (kc*2 + sub)*64 + l (16B); row = sub*16+(l&15), k = kc*32+(l>>4)*8+e
__global__ void pack_x(const float* __restrict__ seg, const int* __restrict__ labels,
                       const float* __restrict__ emb, u16* __restrict__ xpack) {
  __shared__ float ls[32][65];
  __shared__ int lbl[32];
  const int bid = blockIdx.x;
  const int t = bid & (NT - 1);
  const int m = bid >> 9;                    // 0..7
  const int tid = threadIdx.x;
  u16* outb = xpack + (size_t)(m * NT + t) * (XKC * 2 * 64 * 8);
  const int r = tid >> 3, qq = tid & 7;      // 32 rows x 8 col-chunks
  const int l = tid & 63;

  for (int kc2 = 0; kc2 < 16; ++kc2) {       // stage 64 cols of seg at a time
    const float* s = seg + ((size_t)(m * 32 + r) * NT + t) * NH + kc2 * 64 + qq * 8;
    float4 a = ((const float4*)s)[0];
    float4 b2 = ((const float4*)s)[1];
    ls[r][qq * 8 + 0] = a.x;  ls[r][qq * 8 + 1] = a.y;
    ls[r][qq * 8 + 2] = a.z;  ls[r][qq * 8 + 3] = a.w;
    ls[r][qq * 8 + 4] = b2.x; ls[r][qq * 8 + 5] = b2.y;
    ls[r][qq * 8 + 6] = b2.z; ls[r][qq * 8 + 7] = b2.w;
    __syncthreads();
    const int sub2 = tid >> 6;               // 0..3 -> (kc half, sub)
    const int kc = kc2 * 2 + (sub2 >> 1);
    const int sub = sub2 & 1;
    const int row = sub * 16 + (l & 15);
    const int c0 = (sub2 >> 1) * 32 + (l >> 4) * 8;
    u16 o[8];
#pragma unroll
    for (int e = 0; e < 8; ++e) o[e] = f2h(ls[row][c0 + e]);
    ((uint4*)outb)[(kc * 2 + sub) * 64 + l] = pack8h(o);
    __syncthreads();
  }
  if (tid < 32)
    lbl[tid] = (t == 0) ? NL : labels[(size_t)(m * 32 + tid) * NT + (t - 1)];
  __syncthreads();
#pragma unroll
  for (int k = 0; k < 2; ++k) {
    int u = tid + k * 256;                   // 512 units: kc 32..35, sub, l
    int kc = 32 + (u >> 7);
    int sub = (u >> 6) & 1;
    int ll = u & 63;
    int row = sub * 16 + (ll & 15);
    int c = (kc - 32) * 32 + (ll >> 4) * 8;
    const float* s = emb + (size_t)lbl[row] * NE + c;
    float4 a = ((const float4*)s)[0];
    float4 b2 = ((const float4*)s)[1];
    u16 o[8];
    o[0] = f2h(a.x); o[1] = f2h(a.y); o[2] = f2h(a.z); o[3] = f2h(a.w);
    o[4] = f2h(b2.x); o[5] = f2h(b2.y); o[6] = f2h(b2.z); o[7] = f2h(b2.w);
    ((uint4*)outb)[(kc * 2 + sub) * 64 + ll] = pack8h(o);
  }
}

// ---------------- persistent GRU kernel ----------------
#define MFMA16(a, b, c) __builtin_amdgcn_mfma_f32_16x16x32_f16((a), (b), (c), 0, 0, 0)

#define LOADX(i, BA, BB) do { \
  const int kc_ = w * 9 + (i); \
  const size_t xu_ = xbase_u + (size_t)(kc_ * 2) * 64 + l; \
  BA[0] = xp[xu_]; BA[1] = xp[xu_ + 64]; \
  const size_t wu_ = wbase_u + (size_t)(kc_ * 6) * 64 + l; \
  BB[0] = wp[wu_];       BB[1] = wp[wu_ + 64]; \
  BB[2] = wp[wu_ + 128]; BB[3] = wp[wu_ + 192]; \
  BB[4] = wp[wu_ + 256]; BB[5] = wp[wu_ + 320]; \
} while (0)

#define MFMAX(BA, BB) do { \
  _Pragma("unroll") \
  for (int s_ = 0; s_ < 2; ++s_) { \
    half8 a_ = __builtin_bit_cast(half8, BA[s_]); \
    _Pragma("unroll") \
    for (int n_ = 0; n_ < 2; ++n_) { \
      aR[s_][n_]  = MFMA16(a_, __builtin_bit_cast(half8, BB[n_]),     aR[s_][n_]); \
      aZ[s_][n_]  = MFMA16(a_, __builtin_bit_cast(half8, BB[2 + n_]), aZ[s_][n_]); \
      aXN[s_][n_] = MFMA16(a_, __builtin_bit_cast(half8, BB[4 + n_]), aXN[s_][n_]); \
    } \
  } \
} while (0)

#define LOADHB(i, BB) do { \
  const int kc_ = XKC + w * 8 + (i); \
  const size_t wu_ = wbase_u + (size_t)(kc_ * 6) * 64 + l; \
  BB[0] = wp[wu_];       BB[1] = wp[wu_ + 64]; \
  BB[2] = wp[wu_ + 128]; BB[3] = wp[wu_ + 192]; \
  BB[4] = wp[wu_ + 256]; BB[5] = wp[wu_ + 320]; \
} while (0)

#define HA2FRAG(ci, s_, a_) \
  uint4 av_; \
  av_.x = (u32)hA[ci][s_][0]; av_.y = (u32)(hA[ci][s_][0] >> 32); \
  av_.z = (u32)hA[ci][s_][1]; av_.w = (u32)(hA[ci][s_][1] >> 32); \
  half8 a_ = __builtin_bit_cast(half8, av_);

#define MFMAH(ci, BB) do { \
  _Pragma("unroll") \
  for (int s_ = 0; s_ < 2; ++s_) { \
    HA2FRAG(ci, s_, a_) \
    _Pragma("unroll") \
    for (int n_ = 0; n_ < 2; ++n_) { \
      aR[s_][n_]  = MFMA16(a_, __builtin_bit_cast(half8, BB[n_]),     aR[s_][n_]); \
      aZ[s_][n_]  = MFMA16(a_, __builtin_bit_cast(half8, BB[2 + n_]), aZ[s_][n_]); \
      aHN[s_][n_] = MFMA16(a_, __builtin_bit_cast(half8, BB[4 + n_]), aHN[s_][n_]); \
    } \
  } \
} while (0)

#define MFMAL(ci, OO) do { \
  _Pragma("unroll") \
  for (int s_ = 0; s_ < 2; ++s_) { \
    HA2FRAG(ci, s_, a_) \
    aL[s_][0] = MFMA16(a_, __builtin_bit_cast(half8, OO[0]), aL[s_][0]); \
    aL[s_][1] = MFMA16(a_, __builtin_bit_cast(half8, OO[1]), aL[s_][1]); \
  } \
} while (0)

__global__ __launch_bounds__(THREADS, 1)
void gru_persist(const u16* __restrict__ xpack, const u16* __restrict__ wpack,
                 const u16* __restrict__ wopack,
                 const float* __restrict__ bih, const float* __restrict__ bhh,
                 const float* __restrict__ bout,
                 u64* __restrict__ hbuf, u32* __restrict__ counters,
                 float* __restrict__ out) {
  __shared__ f32x4 redv[4 * 3 * 4 * 64];     // 48KB f32 exchange
  __shared__ u16 hbf[32 * 40];               // 2.5KB fp16 bounce for h write

  const int bid = blockIdx.x;
  const int xcd = bid & 7;
  const int q = bid >> 3;                    // 0..31
  const int m = q & 7;                       // group (32 rows)
  const int jslot = q >> 3;                  // 0..3
  const int jt = jslot * 8 + xcd;            // 4 distinct jt per XCD -> weights L2-resident
  const int tid = threadIdx.x;
  const int w = tid >> 6, l = tid & 63;
  const int l15 = l & 15, l4 = l >> 4;
  const int sub_w = w & 1, ni_w = w >> 1;    // this wave's owned output subtile

  const uint4* xp = (const uint4*)xpack;
  const uint4* wp = (const uint4*)wpack;
  const uint4* wo = (const uint4*)wopack;
  u32* cnt = counters + m * 16;
  const size_t wbase_u = (size_t)jt * (KCT * 6 * 64);

  // biases for this wave's owned columns (zero in this problem, honored anyway)
  const int ocol = jt * 32 + ni_w * 16 + l15;
  const float br = bih[ocol] + bhh[ocol];
  const float bz = bih[NH + ocol] + bhh[NH + ocol];
  const float bxn = bih[2 * NH + ocol];
  const float bhn = bhh[2 * NH + ocol];
  float hold[4] = {0.f, 0.f, 0.f, 0.f};
  const f32x4 z4 = {0.f, 0.f, 0.f, 0.f};

  for (int t = 0; t < NT; ++t) {
    const int par = t & 1;
    const size_t xbase_u = (size_t)(m * NT + t) * (XKC * 2 * 64);
    const bool duty = (jt == (t & 31));
    f32x4 aR[2][2], aZ[2][2], aXN[2][2], aHN[2][2];
#pragma unroll
    for (int s_ = 0; s_ < 2; ++s_)
#pragma unroll
      for (int n_ = 0; n_ < 2; ++n_) {
        aR[s_][n_] = z4; aZ[s_][n_] = z4; aXN[s_][n_] = z4; aHN[s_][n_] = z4;
      }

    // ---- x phase (independent; overlaps other blocks' tails) ----
    {
      uint4 xA0[2], xA1[2], xB0[6], xB1[6];
      LOADX(0, xA0, xB0);
#pragma unroll
      for (int i = 0; i < 9; ++i) {
        if ((i & 1) == 0) { if (i < 8) LOADX(i + 1, xA1, xB1); MFMAX(xA0, xB0); }
        else              { if (i < 8) LOADX(i + 1, xA0, xB0); MFMAX(xA1, xB1); }
      }
    }

    // ---- wait for group's h(t) ----
    if (tid == 0) {
      const u32 target = 32u * (u32)t;
      while (__hip_atomic_load(cnt, __ATOMIC_ACQUIRE, __HIP_MEMORY_SCOPE_AGENT) < target)
        __builtin_amdgcn_s_sleep(1);
    }
    __syncthreads();

    // ---- h phase: A-frags via LLC (agent), B streamed double-buffered ----
    u64 hA[8][2][2];
    {
      u64* hb_ = hbuf + (size_t)(par * MT + m) * HB_U64_PER;
#pragma unroll
      for (int c_ = 0; c_ < 8; ++c_) {
        const int kc_ = w * 8 + c_;
#pragma unroll
        for (int s_ = 0; s_ < 2; ++s_) {
          const size_t o_ = ((size_t)(kc_ * 2 + s_) * 64 + l) * 2;
          hA[c_][s_][0] = __hip_atomic_load(hb_ + o_, __ATOMIC_RELAXED, __HIP_MEMORY_SCOPE_AGENT);
          hA[c_][s_][1] = __hip_atomic_load(hb_ + o_ + 1, __ATOMIC_RELAXED, __HIP_MEMORY_SCOPE_AGENT);
        }
      }
    }
    {
      uint4 hB0[6], hB1[6];
      LOADHB(0, hB0);
#pragma unroll
      for (int i = 0; i < 8; ++i) {
        if ((i & 1) == 0) { if (i < 7) LOADHB(i + 1, hB1); MFMAH(i, hB0); }
        else              { if (i < 7) LOADHB(i + 1, hB0); MFMAH(i, hB1); }
      }
    }

    // ---- cross-wave k-reduction (f32), wave w owns (sub_w, ni_w) ----
    f32x4 sR, sZ, sXN, sHN;
#pragma unroll
    for (int o = 0; o < 4; ++o) {
      if (o == w) {
        sR = aR[sub_w][ni_w]; sZ = aZ[sub_w][ni_w];
        sXN = aXN[sub_w][ni_w]; sHN = aHN[sub_w][ni_w];
      } else {
        const int slot = (w > o) ? (w - 1) : w;
        const int os = o & 1, on = o >> 1;
        redv[((o * 3 + slot) * 4 + 0) * 64 + l] = aR[os][on];
        redv[((o * 3 + slot) * 4 + 1) * 64 + l] = aZ[os][on];
        redv[((o * 3 + slot) * 4 + 2) * 64 + l] = aXN[os][on];
        redv[((o * 3 + slot) * 4 + 3) * 64 + l] = aHN[os][on];
      }
    }
    __syncthreads();
#pragma unroll
    for (int slot = 0; slot < 3; ++slot) {
      sR  += redv[((w * 3 + slot) * 4 + 0) * 64 + l];
      sZ  += redv[((w * 3 + slot) * 4 + 1) * 64 + l];
      sXN += redv[((w * 3 + slot) * 4 + 2) * 64 + l];
      sHN += redv[((w * 3 + slot) * 4 + 3) * 64 + l];
    }

    // ---- gate math (fp32 carried state) ----
#pragma unroll
    for (int rg = 0; rg < 4; ++rg) {
      float R = sR[rg] + br;
      float Z = sZ[rg] + bz;
      float XNv = sXN[rg] + bxn;
      float HNv = sHN[rg] + bhn;
      float r_ = 1.f / (1.f + __expf(-R));
      float z_ = 1.f / (1.f + __expf(-Z));
      float pre = XNv + r_ * HNv;
      float e2 = __expf(2.f * pre);
      float n_ = 1.f - 2.f / (e2 + 1.f);
      float hn_ = (1.f - z_) * n_ + z_ * hold[rg];
      hold[rg] = hn_;
      hbf[(sub_w * 16 + l4 * 4 + rg) * 40 + ni_w * 16 + l15] = f2h(hn_);
    }
    __syncthreads();

    // ---- write h(t+1) chunk kc=jt (waves 0,1 = sub 0,1) ----
    if (w < 2) {
      const int row = w * 16 + l15;
      const uint4 hv = *(const uint4*)&hbf[(size_t)row * 40 + l4 * 8];
      u64 lo = ((u64)hv.y << 32) | (u64)hv.x;
      u64 hi = ((u64)hv.w << 32) | (u64)hv.z;
      u64* dst = hbuf + (size_t)((par ^ 1) * MT + m) * HB_U64_PER
                      + ((size_t)(jt * 2 + w) * 64 + l) * 2;
      __hip_atomic_store(dst, lo, __ATOMIC_RELAXED, __HIP_MEMORY_SCOPE_AGENT);
      __hip_atomic_store(dst + 1, hi, __ATOMIC_RELAXED, __HIP_MEMORY_SCOPE_AGENT);
    }
    __syncthreads();   // drains stores (compiler emits vmcnt(0) before barrier)
    if (tid == 0)
      __hip_atomic_fetch_add(cnt, 1u, __ATOMIC_RELEASE, __HIP_MEMORY_SCOPE_AGENT);

    // ---- rotating duty block: logits[:, t-1] from live hA (post-signal) ----
    if (duty && t > 0) {
      f32x4 aL[2][2];
      aL[0][0] = z4; aL[0][1] = z4; aL[1][0] = z4; aL[1][1] = z4;
#pragma unroll
      for (int c_ = 0; c_ < 8; ++c_) {
        uint4 OO[2];
        OO[0] = wo[(size_t)((w * 8 + c_) * 2 + 0) * 64 + l];
        OO[1] = wo[(size_t)((w * 8 + c_) * 2 + 1) * 64 + l];
        MFMAL(c_, OO);
      }
      f32x4 sL;
#pragma unroll
      for (int o = 0; o < 4; ++o) {
        if (o == w) sL = aL[sub_w][ni_w];
        else {
          const int slot = (w > o) ? (w - 1) : w;
          redv[((o * 3 + slot) * 4) * 64 + l] = aL[o & 1][o >> 1];
        }
      }
      __syncthreads();
#pragma unroll
      for (int slot = 0; slot < 3; ++slot)
        sL += redv[((w * 3 + slot) * 4) * 64 + l];
      const int col = ni_w * 16 + l15;
      if (col < NL) {
#pragma unroll
        for (int rg = 0; rg < 4; ++rg) {
          const int row = sub_w * 16 + l4 * 4 + rg;
          const size_t b_ = (size_t)m * 32 + row;
          out[(b_ * NT + (t - 1)) * NL + col] = sL[rg] + bout[col];
        }
      }
      __syncthreads();
    }
  }

  // ---- epilogue: logits[:, 511] from h_512 (parity 0), one block per group ----
  if (jt == 0) {
    if (tid == 0) {
      while (__hip_atomic_load(cnt, __ATOMIC_ACQUIRE, __HIP_MEMORY_SCOPE_AGENT) < 32u * 512u)
        __builtin_amdgcn_s_sleep(1);
    }
    __syncthreads();
    u64 hA[8][2][2];
    u64* hb_ = hbuf + (size_t)(0 * MT + m) * HB_U64_PER;
#pragma unroll
    for (int c_ = 0; c_ < 8; ++c_) {
      const int kc_ = w * 8 + c_;
#pragma unroll
      for (int s_ = 0; s_ < 2; ++s_) {
        const size_t o_ = ((size_t)(kc_ * 2 + s_) * 64 + l) * 2;
        hA[c_][s_][0] = __hip_atomic_load(hb_ + o_, __ATOMIC_RELAXED, __HIP_MEMORY_SCOPE_AGENT);
        hA[c_][s_][1] = __hip_atomic_load(hb_ + o_ + 1, __ATOMIC_RELAXED, __HIP_MEMORY_SCOPE_AGENT);
      }
    }
    f32x4 aL[2][2];
    const f32x4 z4b = {0.f, 0.f, 0.f, 0.f};
    aL[0][0] = z4b; aL[0][1] = z4b; aL[1][0] = z4b; aL[1][1] = z4b;
#pragma unroll
    for (int c_ = 0; c_ < 8; ++c_) {
      uint4 OO[2];
      OO[0] = wo[(size_t)((w * 8 + c_) * 2 + 0) * 64 + l];
      OO[1] = wo[(size_t)((w * 8 + c_) * 2 + 1) * 64 + l];
      MFMAL(c_, OO);
    }
    f32x4 sL;
#pragma unroll
    for (int o = 0; o < 4; ++o) {
      if (o == w) sL = aL[sub_w][ni_w];
      else {
        const int slot = (w > o) ? (w - 1) : w;
        redv[((o * 3 + slot) * 4) * 64 + l] = aL[o & 1][o >> 1];
      }
    }
    __syncthreads();
#pragma unroll
    for (int slot = 0; slot < 3; ++slot)
      sL += redv[((w * 3 + slot) * 4) * 64 + l];
    const int col = ni_w * 16 + l15;
    if (col < NL) {
#pragma unroll
      for (int rg = 0; rg < 4; ++rg) {
        const int row = sub_w * 16 + l4 * 4 + rg;
        const size_t b_ = (size_t)m * 32 + row;
        out[(b_ * NT + 511) * NL + col] = sL[rg] + bout[col];
      }
    }
  }
}

extern "C" void kernel_launch(void* const* d_in, const int* in_sizes, int n_in,
                              void* d_out, int out_size, void* d_ws, size_t ws_size,
                              hipStream_t stream) {
  (void)in_sizes; (void)n_in; (void)out_size;
  const float* seg   = (const float*)d_in[0];
  const int*   labels= (const int*)d_in[1];
  const float* emb   = (const float*)d_in[2];
  const float* Wih   = (const float*)d_in[3];
  const float* Whh   = (const float*)d_in[4];
  const float* bih   = (const float*)d_in[5];
  const float* bhh   = (const float*)d_in[6];
  const float* Wout  = (const float*)d_in[7];
  const float* bout  = (const float*)d_in[8];
  float* out = (float*)d_out;
  char* ws = (char*)d_ws;
  if (ws_size < WS_TOTAL) return;

  zero_ws<<<129, 256, 0, stream>>>((uint4*)(ws + WS_CNT));
  pack_w<<<3280, 256, 0, stream>>>(Wih, Whh, Wout,
                                   (u16*)(ws + WS_WPACK), (u16*)(ws + WS_WOPACK));
  pack_x<<<4096, 256, 0, stream>>>(seg, labels, emb, (u16*)(ws + WS_XPACK));
  gru_persist<<<NBLK, THREADS, 0, stream>>>(
      (const u16*)(ws + WS_XPACK), (const u16*)(ws + WS_WPACK),
      (const u16*)(ws + WS_WOPACK), bih, bhh, bout,
      (u64*)(ws + WS_HBUF), (u32*)(ws + WS_CNT), out);
}

// Round 5
// 10444.051 us; speedup vs baseline: 1.7767x; 1.5067x over previous
//
#include <hip/hip_runtime.h>
#include <hip/hip_fp16.h>

typedef unsigned short u16;
typedef unsigned int u32;
typedef unsigned long long u64;

#define NT 512      // time steps
#define NB 256      // batch
#define NH 1024     // hidden
#define NE 128      // emb dim
#define NHE 1152    // H+E
#define NL 17       // labels
#define MT 8        // batch groups (32 rows each)
#define JTILES 32   // hidden-col tiles (32 cols each)
#define XKC 36      // K-chunks (32 wide) for x part
#define HKC 32      // K-chunks for h part
#define KCT 68      // XKC + HKC
#define NBLK 256    // MT * JTILES
#define THREADS 256

typedef __attribute__((ext_vector_type(8))) _Float16 half8;
typedef __attribute__((ext_vector_type(4))) float f32x4;

// ---- workspace layout (bytes) ----
// hbuf: 2 parity * 8 groups * (32kc * 2sub * 64l * 16B) = 1,048,576
#define WS_CNT     0ull
#define WS_HBUF    4096ull
#define WS_WPACK   1052672ull                // 32*68*6*1024     = 13,369,344
#define WS_WOPACK  14422016ull               // 32*2*1024        = 65,536
#define WS_XPACK   14487552ull               // 8*512*36*2*64*16 = 301,989,888
#define WS_TOTAL   316477440ull

#define HB_U64_PER (HKC * 2 * 64 * 2)        // 8192 u64 per (par,m)

__device__ __forceinline__ u16 f2h(float f) {
  __half h = __float2half(f);
  return __builtin_bit_cast(u16, h);
}
__device__ __forceinline__ uint4 pack8h(const u16* o) {
  uint4 v;
  v.x = (u32)o[0] | ((u32)o[1] << 16);
  v.y = (u32)o[2] | ((u32)o[3] << 16);
  v.z = (u32)o[4] | ((u32)o[5] << 16);
  v.w = (u32)o[6] | ((u32)o[7] << 16);
  return v;
}

// ---------------- zero counters + h parity-0 ----------------
__global__ void zero_ws(uint4* p) {
  // cnt 4096B + parity-0 hbuf 524288B = 33024 uint4
  int idx = blockIdx.x * 256 + threadIdx.x;
  if (idx < 33024) {
    uint4 z; z.x = 0; z.y = 0; z.z = 0; z.w = 0;
    p[idx] = z;
  }
}

// ---------------- pack weights into B-fragment order ----------------
// wpack unit: (((jt*KCT+kc)*3+g)*2+ni)*64 + l  (16B each)
// B-frag: col = jt*32 + ni*16 + (l&15), k = kc*32 + (l>>4)*8 + e
__global__ void pack_w(const float* __restrict__ Wih, const float* __restrict__ Whh,
                       const float* __restrict__ Wout, u16* __restrict__ wpack,
                       u16* __restrict__ wopack) {
  int idx = blockIdx.x * 256 + threadIdx.x;
  const int WUNITS = JTILES * KCT * 3 * 2 * 64;   // 835584
  if (idx < WUNITS) {
    int l = idx & 63;
    int r = idx >> 6;
    int ni = r & 1; r >>= 1;
    int g = r % 3;  r /= 3;
    int kc = r % KCT; r /= KCT;
    int jt = r;
    int row = g * NH + jt * 32 + ni * 16 + (l & 15);
    int kk = (l >> 4) * 8;
    const float* src = (kc < XKC) ? (Wih + (size_t)row * NHE + kc * 32 + kk)
                                  : (Whh + (size_t)row * NH + (kc - XKC) * 32 + kk);
    u16 o[8];
#pragma unroll
    for (int e = 0; e < 8; ++e) o[e] = f2h(src[e]);
    ((uint4*)wpack)[idx] = pack8h(o);
  } else if (idx < WUNITS + HKC * 2 * 64) {
    int j = idx - WUNITS;
    int l = j & 63; j >>= 6;
    int ni = j & 1; int kc = j >> 1;
    int col = (l & 15) + 16 * ni;
    int kk = kc * 32 + (l >> 4) * 8;
    u16 o[8];
#pragma unroll
    for (int e = 0; e < 8; ++e)
      o[e] = (col < NL) ? f2h(Wout[(size_t)col * NH + kk + e]) : (u16)0;
    ((uint4*)wopack)[idx - WUNITS] = pack8h(o);
  }
}

// ---------------- pack x = [seg | emb(prev)] into A-fragment order ----------------
// xpack unit per (m,t): (kc*2 + sub)*64 + l (16B); row = sub*16+(l&15), k = kc*32+(l>>4)*8+e
__global__ void pack_x(const float* __restrict__ seg, const int* __restrict__ labels,
                       const float* __restrict__ emb, u16* __restrict__ xpack) {
  __shared__ float ls[32][65];
  __shared__ int lbl[32];
  const int bid = blockIdx.x;
  const int t = bid & (NT - 1);
  const int m = bid >> 9;                    // 0..7
  const int tid = threadIdx.x;
  u16* outb = xpack + (size_t)(m * NT + t) * (XKC * 2 * 64 * 8);
  const int r = tid >> 3, qq = tid & 7;      // 32 rows x 8 col-chunks
  const int l = tid & 63;

  for (int kc2 = 0; kc2 < 16; ++kc2) {       // stage 64 cols of seg at a time
    const float* s = seg + ((size_t)(m * 32 + r) * NT + t) * NH + kc2 * 64 + qq * 8;
    float4 a = ((const float4*)s)[0];
    float4 b2 = ((const float4*)s)[1];
    ls[r][qq * 8 + 0] = a.x;  ls[r][qq * 8 + 1] = a.y;
    ls[r][qq * 8 + 2] = a.z;  ls[r][qq * 8 + 3] = a.w;
    ls[r][qq * 8 + 4] = b2.x; ls[r][qq * 8 + 5] = b2.y;
    ls[r][qq * 8 + 6] = b2.z; ls[r][qq * 8 + 7] = b2.w;
    __syncthreads();
    const int sub2 = tid >> 6;               // 0..3 -> (kc half, sub)
    const int kc = kc2 * 2 + (sub2 >> 1);
    const int sub = sub2 & 1;
    const int row = sub * 16 + (l & 15);
    const int c0 = (sub2 >> 1) * 32 + (l >> 4) * 8;
    u16 o[8];
#pragma unroll
    for (int e = 0; e < 8; ++e) o[e] = f2h(ls[row][c0 + e]);
    ((uint4*)outb)[(kc * 2 + sub) * 64 + l] = pack8h(o);
    __syncthreads();
  }
  if (tid < 32)
    lbl[tid] = (t == 0) ? NL : labels[(size_t)(m * 32 + tid) * NT + (t - 1)];
  __syncthreads();
#pragma unroll
  for (int k = 0; k < 2; ++k) {
    int u = tid + k * 256;                   // 512 units: kc 32..35, sub, l
    int kc = 32 + (u >> 7);
    int sub = (u >> 6) & 1;
    int ll = u & 63;
    int row = sub * 16 + (ll & 15);
    int c = (kc - 32) * 32 + (ll >> 4) * 8;
    const float* s = emb + (size_t)lbl[row] * NE + c;
    float4 a = ((const float4*)s)[0];
    float4 b2 = ((const float4*)s)[1];
    u16 o[8];
    o[0] = f2h(a.x); o[1] = f2h(a.y); o[2] = f2h(a.z); o[3] = f2h(a.w);
    o[4] = f2h(b2.x); o[5] = f2h(b2.y); o[6] = f2h(b2.z); o[7] = f2h(b2.w);
    ((uint4*)outb)[(kc * 2 + sub) * 64 + ll] = pack8h(o);
  }
}

// ---------------- persistent GRU kernel ----------------
#define MFMA16(a, b, c) __builtin_amdgcn_mfma_f32_16x16x32_f16((a), (b), (c), 0, 0, 0)

#define LOADX(i, BA, BB) do { \
  const int kc_ = w * 9 + (i); \
  const size_t xu_ = xbase_u + (size_t)(kc_ * 2) * 64 + l; \
  BA[0] = xp[xu_]; BA[1] = xp[xu_ + 64]; \
  const size_t wu_ = wbase_u + (size_t)(kc_ * 6) * 64 + l; \
  BB[0] = wp[wu_];       BB[1] = wp[wu_ + 64]; \
  BB[2] = wp[wu_ + 128]; BB[3] = wp[wu_ + 192]; \
  BB[4] = wp[wu_ + 256]; BB[5] = wp[wu_ + 320]; \
} while (0)

// h-phase: A-frags from LDS (ds_read_b128), B from L2-resident wpack
#define LOADH(i, BA, BB) do { \
  const int kc_ = w * 8 + (i); \
  BA[0] = hlds[(kc_ * 2 + 0) * 64 + l]; \
  BA[1] = hlds[(kc_ * 2 + 1) * 64 + l]; \
  const size_t wu_ = wbase_u + (size_t)((XKC + kc_) * 6) * 64 + l; \
  BB[0] = wp[wu_];       BB[1] = wp[wu_ + 64]; \
  BB[2] = wp[wu_ + 128]; BB[3] = wp[wu_ + 192]; \
  BB[4] = wp[wu_ + 256]; BB[5] = wp[wu_ + 320]; \
} while (0)

#define MFMA3(BA, BB, A3) do { \
  _Pragma("unroll") \
  for (int s_ = 0; s_ < 2; ++s_) { \
    half8 a_ = __builtin_bit_cast(half8, BA[s_]); \
    _Pragma("unroll") \
    for (int n_ = 0; n_ < 2; ++n_) { \
      aR[s_][n_] = MFMA16(a_, __builtin_bit_cast(half8, BB[n_]),     aR[s_][n_]); \
      aZ[s_][n_] = MFMA16(a_, __builtin_bit_cast(half8, BB[2 + n_]), aZ[s_][n_]); \
      A3[s_][n_] = MFMA16(a_, __builtin_bit_cast(half8, BB[4 + n_]), A3[s_][n_]); \
    } \
  } \
} while (0)

#define LOADL(i, BA, OO) do { \
  const int kc_ = w * 8 + (i); \
  BA[0] = hlds[(kc_ * 2 + 0) * 64 + l]; \
  BA[1] = hlds[(kc_ * 2 + 1) * 64 + l]; \
  OO[0] = wo[(size_t)(kc_ * 2 + 0) * 64 + l]; \
  OO[1] = wo[(size_t)(kc_ * 2 + 1) * 64 + l]; \
} while (0)

#define MFMAL(BA, OO) do { \
  _Pragma("unroll") \
  for (int s_ = 0; s_ < 2; ++s_) { \
    half8 a_ = __builtin_bit_cast(half8, BA[s_]); \
    aL[s_][0] = MFMA16(a_, __builtin_bit_cast(half8, OO[0]), aL[s_][0]); \
    aL[s_][1] = MFMA16(a_, __builtin_bit_cast(half8, OO[1]), aL[s_][1]); \
  } \
} while (0)

// stage group h tile (parity p_) from hbuf into hlds; barrier after
#define STAGE_H(p_) do { \
  const u64* hb_ = (const u64*)hbuf + (size_t)((p_) * MT + m) * HB_U64_PER; \
  u64 ta_[16], tb_[16]; \
  _Pragma("unroll") \
  for (int k_ = 0; k_ < 16; ++k_) { \
    const size_t u_ = (size_t)tid + k_ * 256; \
    ta_[k_] = __hip_atomic_load(hb_ + u_ * 2,     __ATOMIC_RELAXED, __HIP_MEMORY_SCOPE_AGENT); \
    tb_[k_] = __hip_atomic_load(hb_ + u_ * 2 + 1, __ATOMIC_RELAXED, __HIP_MEMORY_SCOPE_AGENT); \
  } \
  _Pragma("unroll") \
  for (int k_ = 0; k_ < 16; ++k_) { \
    const int u_ = tid + k_ * 256; \
    uint4 v_; \
    v_.x = (u32)ta_[k_]; v_.y = (u32)(ta_[k_] >> 32); \
    v_.z = (u32)tb_[k_]; v_.w = (u32)(tb_[k_] >> 32); \
    hlds[u_] = v_; \
  } \
  __syncthreads(); \
} while (0)

__global__ __launch_bounds__(THREADS, 1)
void gru_persist(const u16* __restrict__ xpack, const u16* __restrict__ wpack,
                 const u16* __restrict__ wopack,
                 const float* __restrict__ bih, const float* __restrict__ bhh,
                 const float* __restrict__ bout,
                 u64* __restrict__ hbuf, u32* __restrict__ counters,
                 float* __restrict__ out) {
  __shared__ uint4 hlds[HKC * 2 * 64];       // 64KB: h(t) tile, fragment-linear
  __shared__ f32x4 redv[4 * 3 * 4 * 64];     // 48KB f32 exchange
  __shared__ u16 hbf[32 * 40];               // 2.5KB fp16 bounce for h write

  const int bid = blockIdx.x;
  const int xcd = bid & 7;
  const int q = bid >> 3;                    // 0..31
  const int m = q & 7;                       // group (32 rows)
  const int jslot = q >> 3;                  // 0..3
  const int jt = jslot * 8 + xcd;            // 4 distinct jt per XCD -> weights L2-resident
  const int tid = threadIdx.x;
  const int w = tid >> 6, l = tid & 63;
  const int l15 = l & 15, l4 = l >> 4;
  const int sub_w = w & 1, ni_w = w >> 1;    // this wave's owned output subtile

  const uint4* xp = (const uint4*)xpack;
  const uint4* wp = (const uint4*)wpack;
  const uint4* wo = (const uint4*)wopack;
  u32* cnt = counters + m * 16;
  const size_t wbase_u = (size_t)jt * (KCT * 6 * 64);

  // biases for this wave's owned columns (zero here, honored anyway)
  const int ocol = jt * 32 + ni_w * 16 + l15;
  const float br = bih[ocol] + bhh[ocol];
  const float bz = bih[NH + ocol] + bhh[NH + ocol];
  const float bxn = bih[2 * NH + ocol];
  const float bhn = bhh[2 * NH + ocol];
  float hold[4] = {0.f, 0.f, 0.f, 0.f};
  const f32x4 z4 = {0.f, 0.f, 0.f, 0.f};

  for (int t = 0; t < NT; ++t) {
    const int par = t & 1;
    const size_t xbase_u = (size_t)(m * NT + t) * (XKC * 2 * 64);
    const bool duty = (jt == (t & 31));
    f32x4 aR[2][2], aZ[2][2], aXN[2][2], aHN[2][2];
#pragma unroll
    for (int s_ = 0; s_ < 2; ++s_)
#pragma unroll
      for (int n_ = 0; n_ < 2; ++n_) {
        aR[s_][n_] = z4; aZ[s_][n_] = z4; aXN[s_][n_] = z4; aHN[s_][n_] = z4;
      }

    // ---- x phase (independent; overlaps other blocks' tails) ----
    {
      uint4 xA0[2], xA1[2], xB0[6], xB1[6];
      LOADX(0, xA0, xB0);
#pragma unroll
      for (int i = 0; i < 9; ++i) {
        if ((i & 1) == 0) { if (i < 8) LOADX(i + 1, xA1, xB1); MFMA3(xA0, xB0, aXN); }
        else              { if (i < 8) LOADX(i + 1, xA0, xB0); MFMA3(xA1, xB1, aXN); }
      }
    }

    // ---- wait for group's h(t): relaxed spin (no cache-invalidating acquire) ----
    if (tid == 0) {
      const u32 target = 32u * (u32)t;
      while (__hip_atomic_load(cnt, __ATOMIC_RELAXED, __HIP_MEMORY_SCOPE_AGENT) < target)
        __builtin_amdgcn_s_sleep(1);
    }
    __syncthreads();

    // ---- stage h(t) into LDS (coherent LLC reads, one latency) ----
    STAGE_H(par);

    // ---- h phase: A from LDS, B streamed from L2, double-buffered ----
    {
      uint4 hA0[2], hA1[2], hB0[6], hB1[6];
      LOADH(0, hA0, hB0);
#pragma unroll
      for (int i = 0; i < 8; ++i) {
        if ((i & 1) == 0) { if (i < 7) LOADH(i + 1, hA1, hB1); MFMA3(hA0, hB0, aHN); }
        else              { if (i < 7) LOADH(i + 1, hA0, hB0); MFMA3(hA1, hB1, aHN); }
      }
    }

    // ---- cross-wave k-reduction (f32), wave w owns (sub_w, ni_w) ----
    f32x4 sR, sZ, sXN, sHN;
#pragma unroll
    for (int o = 0; o < 4; ++o) {
      if (o == w) {
        sR = aR[sub_w][ni_w]; sZ = aZ[sub_w][ni_w];
        sXN = aXN[sub_w][ni_w]; sHN = aHN[sub_w][ni_w];
      } else {
        const int slot = (w > o) ? (w - 1) : w;
        const int os = o & 1, on = o >> 1;
        redv[((o * 3 + slot) * 4 + 0) * 64 + l] = aR[os][on];
        redv[((o * 3 + slot) * 4 + 1) * 64 + l] = aZ[os][on];
        redv[((o * 3 + slot) * 4 + 2) * 64 + l] = aXN[os][on];
        redv[((o * 3 + slot) * 4 + 3) * 64 + l] = aHN[os][on];
      }
    }
    __syncthreads();
#pragma unroll
    for (int slot = 0; slot < 3; ++slot) {
      sR  += redv[((w * 3 + slot) * 4 + 0) * 64 + l];
      sZ  += redv[((w * 3 + slot) * 4 + 1) * 64 + l];
      sXN += redv[((w * 3 + slot) * 4 + 2) * 64 + l];
      sHN += redv[((w * 3 + slot) * 4 + 3) * 64 + l];
    }

    // ---- gate math (fp32 carried state) ----
#pragma unroll
    for (int rg = 0; rg < 4; ++rg) {
      float R = sR[rg] + br;
      float Z = sZ[rg] + bz;
      float XNv = sXN[rg] + bxn;
      float HNv = sHN[rg] + bhn;
      float r_ = 1.f / (1.f + __expf(-R));
      float z_ = 1.f / (1.f + __expf(-Z));
      float pre = XNv + r_ * HNv;
      float e2 = __expf(2.f * pre);
      float n_ = 1.f - 2.f / (e2 + 1.f);
      float hn_ = (1.f - z_) * n_ + z_ * hold[rg];
      hold[rg] = hn_;
      hbf[(sub_w * 16 + l4 * 4 + rg) * 40 + ni_w * 16 + l15] = f2h(hn_);
    }
    __syncthreads();

    // ---- write h(t+1) chunk kc=jt (waves 0,1 = sub 0,1) ----
    if (w < 2) {
      const int row = w * 16 + l15;
      const uint4 hv = *(const uint4*)&hbf[(size_t)row * 40 + l4 * 8];
      u64 lo = ((u64)hv.y << 32) | (u64)hv.x;
      u64 hi = ((u64)hv.w << 32) | (u64)hv.z;
      u64* dst = hbuf + (size_t)((par ^ 1) * MT + m) * HB_U64_PER
                      + ((size_t)(jt * 2 + w) * 64 + l) * 2;
      __hip_atomic_store(dst, lo, __ATOMIC_RELAXED, __HIP_MEMORY_SCOPE_AGENT);
      __hip_atomic_store(dst + 1, hi, __ATOMIC_RELAXED, __HIP_MEMORY_SCOPE_AGENT);
    }
    __syncthreads();   // drains stores (vmcnt(0) before barrier)
    if (tid == 0)
      __hip_atomic_fetch_add(cnt, 1u, __ATOMIC_RELEASE, __HIP_MEMORY_SCOPE_AGENT);

    // ---- rotating duty block: logits[:, t-1] from LDS h(t) (post-signal) ----
    if (duty && t > 0) {
      f32x4 aL[2][2];
      aL[0][0] = z4; aL[0][1] = z4; aL[1][0] = z4; aL[1][1] = z4;
      uint4 lA[2], lO[2];
#pragma unroll
      for (int c_ = 0; c_ < 8; ++c_) {
        LOADL(c_, lA, lO);
        MFMAL(lA, lO);
      }
      f32x4 sL;
#pragma unroll
      for (int o = 0; o < 4; ++o) {
        if (o == w) sL = aL[sub_w][ni_w];
        else {
          const int slot = (w > o) ? (w - 1) : w;
          redv[((o * 3 + slot) * 4) * 64 + l] = aL[o & 1][o >> 1];
        }
      }
      __syncthreads();
#pragma unroll
      for (int slot = 0; slot < 3; ++slot)
        sL += redv[((w * 3 + slot) * 4) * 64 + l];
      const int col = ni_w * 16 + l15;
      if (col < NL) {
#pragma unroll
        for (int rg = 0; rg < 4; ++rg) {
          const int row = sub_w * 16 + l4 * 4 + rg;
          const size_t b_ = (size_t)m * 32 + row;
          out[(b_ * NT + (t - 1)) * NL + col] = sL[rg] + bout[col];
        }
      }
      __syncthreads();
    }
  }

  // ---- epilogue: logits[:, 511] from h_512 (parity 0), blocks jt==0 ----
  if (jt == 0) {
    if (tid == 0) {
      while (__hip_atomic_load(cnt, __ATOMIC_RELAXED, __HIP_MEMORY_SCOPE_AGENT) < 32u * 512u)
        __builtin_amdgcn_s_sleep(1);
    }
    __syncthreads();
    STAGE_H(0);
    f32x4 aL[2][2];
    aL[0][0] = z4; aL[0][1] = z4; aL[1][0] = z4; aL[1][1] = z4;
    uint4 lA[2], lO[2];
#pragma unroll
    for (int c_ = 0; c_ < 8; ++c_) {
      LOADL(c_, lA, lO);
      MFMAL(lA, lO);
    }
    f32x4 sL;
#pragma unroll
    for (int o = 0; o < 4; ++o) {
      if (o == w) sL = aL[sub_w][ni_w];
      else {
        const int slot = (w > o) ? (w - 1) : w;
        redv[((o * 3 + slot) * 4) * 64 + l] = aL[o & 1][o >> 1];
      }
    }
    __syncthreads();
#pragma unroll
    for (int slot = 0; slot < 3; ++slot)
      sL += redv[((w * 3 + slot) * 4) * 64 + l];
    const int col = ni_w * 16 + l15;
    if (col < NL) {
#pragma unroll
      for (int rg = 0; rg < 4; ++rg) {
        const int row = sub_w * 16 + l4 * 4 + rg;
        const size_t b_ = (size_t)m * 32 + row;
        out[(b_ * NT + 511) * NL + col] = sL[rg] + bout[col];
      }
    }
  }
}

extern "C" void kernel_launch(void* const* d_in, const int* in_sizes, int n_in,
                              void* d_out, int out_size, void* d_ws, size_t ws_size,
                              hipStream_t stream) {
  (void)in_sizes; (void)n_in; (void)out_size;
  const float* seg   = (const float*)d_in[0];
  const int*   labels= (const int*)d_in[1];
  const float* emb   = (const float*)d_in[2];
  const float* Wih   = (const float*)d_in[3];
  const float* Whh   = (const float*)d_in[4];
  const float* bih   = (const float*)d_in[5];
  const float* bhh   = (const float*)d_in[6];
  const float* Wout  = (const float*)d_in[7];
  const float* bout  = (const float*)d_in[8];
  float* out = (float*)d_out;
  char* ws = (char*)d_ws;
  if (ws_size < WS_TOTAL) return;

  zero_ws<<<129, 256, 0, stream>>>((uint4*)(ws + WS_CNT));
  pack_w<<<3280, 256, 0, stream>>>(Wih, Whh, Wout,
                                   (u16*)(ws + WS_WPACK), (u16*)(ws + WS_WOPACK));
  pack_x<<<4096, 256, 0, stream>>>(seg, labels, emb, (u16*)(ws + WS_XPACK));
  gru_persist<<<NBLK, THREADS, 0, stream>>>(
      (const u16*)(ws + WS_XPACK), (const u16*)(ws + WS_WPACK),
      (const u16*)(ws + WS_WOPACK), bih, bhh, bout,
      (u64*)(ws + WS_HBUF), (u32*)(ws + WS_CNT), out);
}

// Round 6
// 9940.679 us; speedup vs baseline: 1.8667x; 1.0506x over previous
//
#include <hip/hip_runtime.h>
#include <hip/hip_fp16.h>

typedef unsigned short u16;
typedef unsigned int u32;
typedef unsigned long long u64;

#define NT 512      // time steps
#define NB 256      // batch
#define NH 1024     // hidden
#define NE 128      // emb dim
#define NHE 1152    // H+E
#define NL 17       // labels
#define MT 8        // batch groups (32 rows each)
#define JTILES 32   // hidden-col tiles (32 cols each)
#define XKC 36      // K-chunks (32 wide) for x part
#define HKC 32      // K-chunks for h part
#define KCT 68      // XKC + HKC
#define NBLK 256    // MT * JTILES
#define THREADS 256

typedef __attribute__((ext_vector_type(8))) _Float16 half8;
typedef __attribute__((ext_vector_type(4))) float f32x4;

// ---- workspace layout (bytes) ----
// hbuf: 2 parity * 8 groups * (32kc * 2sub * 64l * 16B) = 1,048,576
#define WS_CNT     0ull
#define WS_HBUF    4096ull
#define WS_WPACK   1052672ull                // 32*68*6*1024     = 13,369,344
#define WS_WOPACK  14422016ull               // 32*2*1024        = 65,536
#define WS_XPACK   14487552ull               // 8*512*36*2*64*16 = 301,989,888
#define WS_TOTAL   316477440ull

#define HB_U64_PER (HKC * 2 * 64 * 2)        // 8192 u64 per (par,m)

__device__ __forceinline__ u16 f2h(float f) {
  __half h = __float2half(f);
  return __builtin_bit_cast(u16, h);
}
__device__ __forceinline__ uint4 pack8h(const u16* o) {
  uint4 v;
  v.x = (u32)o[0] | ((u32)o[1] << 16);
  v.y = (u32)o[2] | ((u32)o[3] << 16);
  v.z = (u32)o[4] | ((u32)o[5] << 16);
  v.w = (u32)o[6] | ((u32)o[7] << 16);
  return v;
}

// direct global->LDS DMA, 16B per lane; aux=17 (sc0|sc1): bypass non-coherent
// per-XCD L2, read from the LLC coherence point where producers' agent-scope
// stores land. LDS dst must be wave-uniform; global src per-lane contiguous.
__device__ __forceinline__ void gll16(const void* g, void* l) {
  __builtin_amdgcn_global_load_lds((const __attribute__((address_space(1))) u32*)g,
                                   (__attribute__((address_space(3))) u32*)l, 16, 0, 17);
}

// ---------------- zero counters + h parity-0 ----------------
__global__ void zero_ws(uint4* p) {
  // cnt 4096B + parity-0 hbuf 524288B = 33024 uint4
  int idx = blockIdx.x * 256 + threadIdx.x;
  if (idx < 33024) {
    uint4 z; z.x = 0; z.y = 0; z.z = 0; z.w = 0;
    p[idx] = z;
  }
}

// ---------------- pack weights into B-fragment order ----------------
// wpack unit: (((jt*KCT+kc)*3+g)*2+ni)*64 + l  (16B each)
// B-frag: col = jt*32 + ni*16 + (l&15), k = kc*32 + (l>>4)*8 + e
__global__ void pack_w(const float* __restrict__ Wih, const float* __restrict__ Whh,
                       const float* __restrict__ Wout, u16* __restrict__ wpack,
                       u16* __restrict__ wopack) {
  int idx = blockIdx.x * 256 + threadIdx.x;
  const int WUNITS = JTILES * KCT * 3 * 2 * 64;   // 835584
  if (idx < WUNITS) {
    int l = idx & 63;
    int r = idx >> 6;
    int ni = r & 1; r >>= 1;
    int g = r % 3;  r /= 3;
    int kc = r % KCT; r /= KCT;
    int jt = r;
    int row = g * NH + jt * 32 + ni * 16 + (l & 15);
    int kk = (l >> 4) * 8;
    const float* src = (kc < XKC) ? (Wih + (size_t)row * NHE + kc * 32 + kk)
                                  : (Whh + (size_t)row * NH + (kc - XKC) * 32 + kk);
    u16 o[8];
#pragma unroll
    for (int e = 0; e < 8; ++e) o[e] = f2h(src[e]);
    ((uint4*)wpack)[idx] = pack8h(o);
  } else if (idx < WUNITS + HKC * 2 * 64) {
    int j = idx - WUNITS;
    int l = j & 63; j >>= 6;
    int ni = j & 1; int kc = j >> 1;
    int col = (l & 15) + 16 * ni;
    int kk = kc * 32 + (l >> 4) * 8;
    u16 o[8];
#pragma unroll
    for (int e = 0; e < 8; ++e)
      o[e] = (col < NL) ? f2h(Wout[(size_t)col * NH + kk + e]) : (u16)0;
    ((uint4*)wopack)[idx - WUNITS] = pack8h(o);
  }
}

// ---------------- pack x = [seg | emb(prev)] into A-fragment order ----------------
// xpack unit per (m,t): (kc*2 + sub)*64 + l (16B); row = sub*16+(l&15), k = kc*32+(l>>4)*8+e
__global__ void pack_x(const float* __restrict__ seg, const int* __restrict__ labels,
                       const float* __restrict__ emb, u16* __restrict__ xpack) {
  __shared__ float ls[32][65];
  __shared__ int lbl[32];
  const int bid = blockIdx.x;
  const int t = bid & (NT - 1);
  const int m = bid >> 9;                    // 0..7
  const int tid = threadIdx.x;
  u16* outb = xpack + (size_t)(m * NT + t) * (XKC * 2 * 64 * 8);
  const int r = tid >> 3, qq = tid & 7;      // 32 rows x 8 col-chunks
  const int l = tid & 63;

  for (int kc2 = 0; kc2 < 16; ++kc2) {       // stage 64 cols of seg at a time
    const float* s = seg + ((size_t)(m * 32 + r) * NT + t) * NH + kc2 * 64 + qq * 8;
    float4 a = ((const float4*)s)[0];
    float4 b2 = ((const float4*)s)[1];
    ls[r][qq * 8 + 0] = a.x;  ls[r][qq * 8 + 1] = a.y;
    ls[r][qq * 8 + 2] = a.z;  ls[r][qq * 8 + 3] = a.w;
    ls[r][qq * 8 + 4] = b2.x; ls[r][qq * 8 + 5] = b2.y;
    ls[r][qq * 8 + 6] = b2.z; ls[r][qq * 8 + 7] = b2.w;
    __syncthreads();
    const int sub2 = tid >> 6;               // 0..3 -> (kc half, sub)
    const int kc = kc2 * 2 + (sub2 >> 1);
    const int sub = sub2 & 1;
    const int row = sub * 16 + (l & 15);
    const int c0 = (sub2 >> 1) * 32 + (l >> 4) * 8;
    u16 o[8];
#pragma unroll
    for (int e = 0; e < 8; ++e) o[e] = f2h(ls[row][c0 + e]);
    ((uint4*)outb)[(kc * 2 + sub) * 64 + l] = pack8h(o);
    __syncthreads();
  }
  if (tid < 32)
    lbl[tid] = (t == 0) ? NL : labels[(size_t)(m * 32 + tid) * NT + (t - 1)];
  __syncthreads();
#pragma unroll
  for (int k = 0; k < 2; ++k) {
    int u = tid + k * 256;                   // 512 units: kc 32..35, sub, l
    int kc = 32 + (u >> 7);
    int sub = (u >> 6) & 1;
    int ll = u & 63;
    int row = sub * 16 + (ll & 15);
    int c = (kc - 32) * 32 + (ll >> 4) * 8;
    const float* s = emb + (size_t)lbl[row] * NE + c;
    float4 a = ((const float4*)s)[0];
    float4 b2 = ((const float4*)s)[1];
    u16 o[8];
    o[0] = f2h(a.x); o[1] = f2h(a.y); o[2] = f2h(a.z); o[3] = f2h(a.w);
    o[4] = f2h(b2.x); o[5] = f2h(b2.y); o[6] = f2h(b2.z); o[7] = f2h(b2.w);
    ((uint4*)outb)[(kc * 2 + sub) * 64 + ll] = pack8h(o);
  }
}

// ---------------- persistent GRU kernel ----------------
#define MFMA16(a, b, c) __builtin_amdgcn_mfma_f32_16x16x32_f16((a), (b), (c), 0, 0, 0)

#define LOADX(i, BA, BB) do { \
  const int kc_ = w * 9 + (i); \
  const size_t xu_ = xbase_u + (size_t)(kc_ * 2) * 64 + l; \
  BA[0] = xp[xu_]; BA[1] = xp[xu_ + 64]; \
  const size_t wu_ = wbase_u + (size_t)(kc_ * 6) * 64 + l; \
  BB[0] = wp[wu_];       BB[1] = wp[wu_ + 64]; \
  BB[2] = wp[wu_ + 128]; BB[3] = wp[wu_ + 192]; \
  BB[4] = wp[wu_ + 256]; BB[5] = wp[wu_ + 320]; \
} while (0)

// h-phase: A-frags from LDS (ds_read_b128), B from L2-resident wpack
#define LOADH(i, BA, BB) do { \
  const int kc_ = w * 8 + (i); \
  BA[0] = hlds[(kc_ * 2 + 0) * 64 + l]; \
  BA[1] = hlds[(kc_ * 2 + 1) * 64 + l]; \
  const size_t wu_ = wbase_u + (size_t)((XKC + kc_) * 6) * 64 + l; \
  BB[0] = wp[wu_];       BB[1] = wp[wu_ + 64]; \
  BB[2] = wp[wu_ + 128]; BB[3] = wp[wu_ + 192]; \
  BB[4] = wp[wu_ + 256]; BB[5] = wp[wu_ + 320]; \
} while (0)

#define MFMA3(BA, BB, A3) do { \
  _Pragma("unroll") \
  for (int s_ = 0; s_ < 2; ++s_) { \
    half8 a_ = __builtin_bit_cast(half8, BA[s_]); \
    _Pragma("unroll") \
    for (int n_ = 0; n_ < 2; ++n_) { \
      aR[s_][n_] = MFMA16(a_, __builtin_bit_cast(half8, BB[n_]),     aR[s_][n_]); \
      aZ[s_][n_] = MFMA16(a_, __builtin_bit_cast(half8, BB[2 + n_]), aZ[s_][n_]); \
      A3[s_][n_] = MFMA16(a_, __builtin_bit_cast(half8, BB[4 + n_]), A3[s_][n_]); \
    } \
  } \
} while (0)

#define LOADL(i, BA, OO) do { \
  const int kc_ = w * 8 + (i); \
  BA[0] = hlds[(kc_ * 2 + 0) * 64 + l]; \
  BA[1] = hlds[(kc_ * 2 + 1) * 64 + l]; \
  OO[0] = wo[(size_t)(kc_ * 2 + 0) * 64 + l]; \
  OO[1] = wo[(size_t)(kc_ * 2 + 1) * 64 + l]; \
} while (0)

#define MFMAL(BA, OO) do { \
  _Pragma("unroll") \
  for (int s_ = 0; s_ < 2; ++s_) { \
    half8 a_ = __builtin_bit_cast(half8, BA[s_]); \
    aL[s_][0] = MFMA16(a_, __builtin_bit_cast(half8, OO[0]), aL[s_][0]); \
    aL[s_][1] = MFMA16(a_, __builtin_bit_cast(half8, OO[1]), aL[s_][1]); \
  } \
} while (0)

// stage group h tile (parity p_) from hbuf into hlds via LDS-DMA; barrier after.
// zero VGPR cost: 16 global_load_lds (wave-uniform LDS base, lane-contiguous src)
#define STAGE_H(p_) do { \
  const char* gb_ = (const char*)hbuf + ((size_t)((p_) * MT + m) * HB_U64_PER) * 8; \
  _Pragma("unroll") \
  for (int k_ = 0; k_ < 16; ++k_) { \
    gll16(gb_ + ((size_t)(k_ * 256 + tid)) * 16, \
          (void*)(hlds + (k_ * 256 + w * 64))); \
  } \
  asm volatile("s_waitcnt vmcnt(0)" ::: "memory"); \
  __syncthreads(); \
} while (0)

__global__ __launch_bounds__(THREADS, 1)
void gru_persist(const u16* __restrict__ xpack, const u16* __restrict__ wpack,
                 const u16* __restrict__ wopack,
                 const float* __restrict__ bih, const float* __restrict__ bhh,
                 const float* __restrict__ bout,
                 u64* __restrict__ hbuf, u32* __restrict__ counters,
                 float* __restrict__ out) {
  __shared__ uint4 hlds[HKC * 2 * 64];       // 64KB: h(t) tile, fragment-linear
  __shared__ f32x4 redv[4 * 3 * 4 * 64];     // 48KB f32 exchange
  __shared__ u16 hbf[32 * 40];               // 2.5KB fp16 bounce for h write

  const int bid = blockIdx.x;
  const int xcd = bid & 7;
  const int q = bid >> 3;                    // 0..31
  const int m = q & 7;                       // group (32 rows)
  const int jslot = q >> 3;                  // 0..3
  const int jt = jslot * 8 + xcd;            // 4 distinct jt per XCD -> weights L2-resident
  const int tid = threadIdx.x;
  const int w = tid >> 6, l = tid & 63;
  const int l15 = l & 15, l4 = l >> 4;
  const int sub_w = w & 1, ni_w = w >> 1;    // this wave's owned output subtile

  const uint4* xp = (const uint4*)xpack;
  const uint4* wp = (const uint4*)wpack;
  const uint4* wo = (const uint4*)wopack;
  u32* cnt = counters + m * 16;
  const size_t wbase_u = (size_t)jt * (KCT * 6 * 64);

  // biases for this wave's owned columns (zero here, honored anyway)
  const int ocol = jt * 32 + ni_w * 16 + l15;
  const float br = bih[ocol] + bhh[ocol];
  const float bz = bih[NH + ocol] + bhh[NH + ocol];
  const float bxn = bih[2 * NH + ocol];
  const float bhn = bhh[2 * NH + ocol];
  float hold[4] = {0.f, 0.f, 0.f, 0.f};
  const f32x4 z4 = {0.f, 0.f, 0.f, 0.f};

  for (int t = 0; t < NT; ++t) {
    const int par = t & 1;
    const size_t xbase_u = (size_t)(m * NT + t) * (XKC * 2 * 64);
    const bool duty = (jt == (t & 31));
    f32x4 aR[2][2], aZ[2][2], aXN[2][2], aHN[2][2];
#pragma unroll
    for (int s_ = 0; s_ < 2; ++s_)
#pragma unroll
      for (int n_ = 0; n_ < 2; ++n_) {
        aR[s_][n_] = z4; aZ[s_][n_] = z4; aXN[s_][n_] = z4; aHN[s_][n_] = z4;
      }

    // ---- x phase (independent; overlaps other blocks' tails) ----
    {
      uint4 xA0[2], xA1[2], xB0[6], xB1[6];
      LOADX(0, xA0, xB0);
#pragma unroll
      for (int i = 0; i < 9; ++i) {
        if ((i & 1) == 0) { if (i < 8) LOADX(i + 1, xA1, xB1); MFMA3(xA0, xB0, aXN); }
        else              { if (i < 8) LOADX(i + 1, xA0, xB0); MFMA3(xA1, xB1, aXN); }
      }
    }

    // ---- wait for group's h(t): relaxed spin ----
    if (tid == 0) {
      const u32 target = 32u * (u32)t;
      while (__hip_atomic_load(cnt, __ATOMIC_RELAXED, __HIP_MEMORY_SCOPE_AGENT) < target)
        __builtin_amdgcn_s_sleep(1);
    }
    __syncthreads();

    // ---- stage h(t) into LDS (DMA, zero registers) ----
    STAGE_H(par);

    // ---- h phase: A from LDS, B streamed from L2, double-buffered ----
    {
      uint4 hA0[2], hA1[2], hB0[6], hB1[6];
      LOADH(0, hA0, hB0);
#pragma unroll
      for (int i = 0; i < 8; ++i) {
        if ((i & 1) == 0) { if (i < 7) LOADH(i + 1, hA1, hB1); MFMA3(hA0, hB0, aHN); }
        else              { if (i < 7) LOADH(i + 1, hA0, hB0); MFMA3(hA1, hB1, aHN); }
      }
    }

    // ---- cross-wave k-reduction (f32), wave w owns (sub_w, ni_w) ----
    f32x4 sR, sZ, sXN, sHN;
#pragma unroll
    for (int o = 0; o < 4; ++o) {
      if (o == w) {
        sR = aR[sub_w][ni_w]; sZ = aZ[sub_w][ni_w];
        sXN = aXN[sub_w][ni_w]; sHN = aHN[sub_w][ni_w];
      } else {
        const int slot = (w > o) ? (w - 1) : w;
        const int os = o & 1, on = o >> 1;
        redv[((o * 3 + slot) * 4 + 0) * 64 + l] = aR[os][on];
        redv[((o * 3 + slot) * 4 + 1) * 64 + l] = aZ[os][on];
        redv[((o * 3 + slot) * 4 + 2) * 64 + l] = aXN[os][on];
        redv[((o * 3 + slot) * 4 + 3) * 64 + l] = aHN[os][on];
      }
    }
    __syncthreads();
#pragma unroll
    for (int slot = 0; slot < 3; ++slot) {
      sR  += redv[((w * 3 + slot) * 4 + 0) * 64 + l];
      sZ  += redv[((w * 3 + slot) * 4 + 1) * 64 + l];
      sXN += redv[((w * 3 + slot) * 4 + 2) * 64 + l];
      sHN += redv[((w * 3 + slot) * 4 + 3) * 64 + l];
    }

    // ---- gate math (fp32 carried state) ----
#pragma unroll
    for (int rg = 0; rg < 4; ++rg) {
      float R = sR[rg] + br;
      float Z = sZ[rg] + bz;
      float XNv = sXN[rg] + bxn;
      float HNv = sHN[rg] + bhn;
      float r_ = 1.f / (1.f + __expf(-R));
      float z_ = 1.f / (1.f + __expf(-Z));
      float pre = XNv + r_ * HNv;
      float e2 = __expf(2.f * pre);
      float n_ = 1.f - 2.f / (e2 + 1.f);
      float hn_ = (1.f - z_) * n_ + z_ * hold[rg];
      hold[rg] = hn_;
      hbf[(sub_w * 16 + l4 * 4 + rg) * 40 + ni_w * 16 + l15] = f2h(hn_);
    }
    __syncthreads();

    // ---- write h(t+1) chunk kc=jt (waves 0,1 = sub 0,1) ----
    if (w < 2) {
      const int row = w * 16 + l15;
      const uint4 hv = *(const uint4*)&hbf[(size_t)row * 40 + l4 * 8];
      u64 lo = ((u64)hv.y << 32) | (u64)hv.x;
      u64 hi = ((u64)hv.w << 32) | (u64)hv.z;
      u64* dst = hbuf + (size_t)((par ^ 1) * MT + m) * HB_U64_PER
                      + ((size_t)(jt * 2 + w) * 64 + l) * 2;
      __hip_atomic_store(dst, lo, __ATOMIC_RELAXED, __HIP_MEMORY_SCOPE_AGENT);
      __hip_atomic_store(dst + 1, hi, __ATOMIC_RELAXED, __HIP_MEMORY_SCOPE_AGENT);
    }
    __syncthreads();   // drains stores (vmcnt(0) before barrier)
    if (tid == 0)
      __hip_atomic_fetch_add(cnt, 1u, __ATOMIC_RELEASE, __HIP_MEMORY_SCOPE_AGENT);

    // ---- rotating duty block: logits[:, t-1] from LDS h(t) (post-signal) ----
    if (duty && t > 0) {
      f32x4 aL[2][2];
      aL[0][0] = z4; aL[0][1] = z4; aL[1][0] = z4; aL[1][1] = z4;
      uint4 lA[2], lO[2];
#pragma unroll
      for (int c_ = 0; c_ < 8; ++c_) {
        LOADL(c_, lA, lO);
        MFMAL(lA, lO);
      }
      f32x4 sL;
#pragma unroll
      for (int o = 0; o < 4; ++o) {
        if (o == w) sL = aL[sub_w][ni_w];
        else {
          const int slot = (w > o) ? (w - 1) : w;
          redv[((o * 3 + slot) * 4) * 64 + l] = aL[o & 1][o >> 1];
        }
      }
      __syncthreads();
#pragma unroll
      for (int slot = 0; slot < 3; ++slot)
        sL += redv[((w * 3 + slot) * 4) * 64 + l];
      const int col = ni_w * 16 + l15;
      if (col < NL) {
#pragma unroll
        for (int rg = 0; rg < 4; ++rg) {
          const int row = sub_w * 16 + l4 * 4 + rg;
          const size_t b_ = (size_t)m * 32 + row;
          out[(b_ * NT + (t - 1)) * NL + col] = sL[rg] + bout[col];
        }
      }
      __syncthreads();
    }
  }

  // ---- epilogue: logits[:, 511] from h_512 (parity 0), blocks jt==0 ----
  if (jt == 0) {
    if (tid == 0) {
      while (__hip_atomic_load(cnt, __ATOMIC_RELAXED, __HIP_MEMORY_SCOPE_AGENT) < 32u * 512u)
        __builtin_amdgcn_s_sleep(1);
    }
    __syncthreads();
    STAGE_H(0);
    f32x4 aL[2][2];
    aL[0][0] = z4; aL[0][1] = z4; aL[1][0] = z4; aL[1][1] = z4;
    uint4 lA[2], lO[2];
#pragma unroll
    for (int c_ = 0; c_ < 8; ++c_) {
      LOADL(c_, lA, lO);
      MFMAL(lA, lO);
    }
    f32x4 sL;
#pragma unroll
    for (int o = 0; o < 4; ++o) {
      if (o == w) sL = aL[sub_w][ni_w];
      else {
        const int slot = (w > o) ? (w - 1) : w;
        redv[((o * 3 + slot) * 4) * 64 + l] = aL[o & 1][o >> 1];
      }
    }
    __syncthreads();
#pragma unroll
    for (int slot = 0; slot < 3; ++slot)
      sL += redv[((w * 3 + slot) * 4) * 64 + l];
    const int col = ni_w * 16 + l15;
    if (col < NL) {
#pragma unroll
      for (int rg = 0; rg < 4; ++rg) {
        const int row = sub_w * 16 + l4 * 4 + rg;
        const size_t b_ = (size_t)m * 32 + row;
        out[(b_ * NT + 511) * NL + col] = sL[rg] + bout[col];
      }
    }
  }
}

extern "C" void kernel_launch(void* const* d_in, const int* in_sizes, int n_in,
                              void* d_out, int out_size, void* d_ws, size_t ws_size,
                              hipStream_t stream) {
  (void)in_sizes; (void)n_in; (void)out_size;
  const float* seg   = (const float*)d_in[0];
  const int*   labels= (const int*)d_in[1];
  const float* emb   = (const float*)d_in[2];
  const float* Wih   = (const float*)d_in[3];
  const float* Whh   = (const float*)d_in[4];
  const float* bih   = (const float*)d_in[5];
  const float* bhh   = (const float*)d_in[6];
  const float* Wout  = (const float*)d_in[7];
  const float* bout  = (const float*)d_in[8];
  float* out = (float*)d_out;
  char* ws = (char*)d_ws;
  if (ws_size < WS_TOTAL) return;

  zero_ws<<<129, 256, 0, stream>>>((uint4*)(ws + WS_CNT));
  pack_w<<<3280, 256, 0, stream>>>(Wih, Whh, Wout,
                                   (u16*)(ws + WS_WPACK), (u16*)(ws + WS_WOPACK));
  pack_x<<<4096, 256, 0, stream>>>(seg, labels, emb, (u16*)(ws + WS_XPACK));
  gru_persist<<<NBLK, THREADS, 0, stream>>>(
      (const u16*)(ws + WS_XPACK), (const u16*)(ws + WS_WPACK),
      (const u16*)(ws + WS_WOPACK), bih, bhh, bout,
      (u64*)(ws + WS_HBUF), (u32*)(ws + WS_CNT), out);
}

// Round 7
// 9885.633 us; speedup vs baseline: 1.8771x; 1.0056x over previous
//
#include <hip/hip_runtime.h>
#include <hip/hip_fp16.h>

typedef unsigned short u16;
typedef unsigned int u32;
typedef unsigned long long u64;

#define NT 512      // time steps
#define NB 256      // batch
#define NH 1024     // hidden
#define NE 128      // emb dim
#define NHE 1152    // H+E
#define NL 17       // labels
#define MT 8        // batch groups (32 rows each)
#define JTILES 32   // hidden-col tiles (32 cols each)
#define XKC 36      // K-chunks (32 wide) for x part
#define HKC 32      // K-chunks for h part
#define KCT 68      // XKC + HKC
#define NBLK 256    // MT * JTILES
#define THREADS 256

typedef __attribute__((ext_vector_type(8))) _Float16 half8;
typedef __attribute__((ext_vector_type(4))) float f32x4;

// ---- workspace layout (bytes) ----
// hbuf: 2 parity * 8 groups * (32kc * 2sub * 64l * 16B) = 1,048,576
#define WS_CNT     0ull
#define WS_HBUF    4096ull
#define WS_WPACK   1052672ull                // 32*68*6*1024     = 13,369,344
#define WS_WOPACK  14422016ull               // 32*2*1024        = 65,536
#define WS_XPACK   14487552ull               // 8*512*36*2*64*16 = 301,989,888
#define WS_TOTAL   316477440ull

#define HB_U64_PER (HKC * 2 * 64 * 2)        // 8192 u64 per (par,m)

__device__ __forceinline__ u16 f2h(float f) {
  __half h = __float2half(f);
  return __builtin_bit_cast(u16, h);
}
__device__ __forceinline__ uint4 pack8h(const u16* o) {
  uint4 v;
  v.x = (u32)o[0] | ((u32)o[1] << 16);
  v.y = (u32)o[2] | ((u32)o[3] << 16);
  v.z = (u32)o[4] | ((u32)o[5] << 16);
  v.w = (u32)o[6] | ((u32)o[7] << 16);
  return v;
}

// direct global->LDS DMA, 16B per lane; aux=17 (sc0|sc1): bypass non-coherent
// per-XCD L2, read at the LLC coherence point where producers' stores land.
__device__ __forceinline__ void gll16(const void* g, void* l) {
  __builtin_amdgcn_global_load_lds((const __attribute__((address_space(1))) u32*)g,
                                   (__attribute__((address_space(3))) u32*)l, 16, 0, 17);
}

// ---------------- zero counters + h parity-0 ----------------
__global__ void zero_ws(uint4* p) {
  int idx = blockIdx.x * 256 + threadIdx.x;
  if (idx < 33024) {
    uint4 z; z.x = 0; z.y = 0; z.z = 0; z.w = 0;
    p[idx] = z;
  }
}

// ---------------- pack weights into B-fragment order ----------------
// wpack unit: (((jt*KCT+kc)*3+g)*2+ni)*64 + l  (16B each)
__global__ void pack_w(const float* __restrict__ Wih, const float* __restrict__ Whh,
                       const float* __restrict__ Wout, u16* __restrict__ wpack,
                       u16* __restrict__ wopack) {
  int idx = blockIdx.x * 256 + threadIdx.x;
  const int WUNITS = JTILES * KCT * 3 * 2 * 64;   // 835584
  if (idx < WUNITS) {
    int l = idx & 63;
    int r = idx >> 6;
    int ni = r & 1; r >>= 1;
    int g = r % 3;  r /= 3;
    int kc = r % KCT; r /= KCT;
    int jt = r;
    int row = g * NH + jt * 32 + ni * 16 + (l & 15);
    int kk = (l >> 4) * 8;
    const float* src = (kc < XKC) ? (Wih + (size_t)row * NHE + kc * 32 + kk)
                                  : (Whh + (size_t)row * NH + (kc - XKC) * 32 + kk);
    u16 o[8];
#pragma unroll
    for (int e = 0; e < 8; ++e) o[e] = f2h(src[e]);
    ((uint4*)wpack)[idx] = pack8h(o);
  } else if (idx < WUNITS + HKC * 2 * 64) {
    int j = idx - WUNITS;
    int l = j & 63; j >>= 6;
    int ni = j & 1; int kc = j >> 1;
    int col = (l & 15) + 16 * ni;
    int kk = kc * 32 + (l >> 4) * 8;
    u16 o[8];
#pragma unroll
    for (int e = 0; e < 8; ++e)
      o[e] = (col < NL) ? f2h(Wout[(size_t)col * NH + kk + e]) : (u16)0;
    ((uint4*)wopack)[idx - WUNITS] = pack8h(o);
  }
}

// ---------------- pack x = [seg | emb(prev)] into A-fragment order ----------------
__global__ void pack_x(const float* __restrict__ seg, const int* __restrict__ labels,
                       const float* __restrict__ emb, u16* __restrict__ xpack) {
  __shared__ float ls[32][65];
  __shared__ int lbl[32];
  const int bid = blockIdx.x;
  const int t = bid & (NT - 1);
  const int m = bid >> 9;                    // 0..7
  const int tid = threadIdx.x;
  u16* outb = xpack + (size_t)(m * NT + t) * (XKC * 2 * 64 * 8);
  const int r = tid >> 3, qq = tid & 7;      // 32 rows x 8 col-chunks
  const int l = tid & 63;

  for (int kc2 = 0; kc2 < 16; ++kc2) {       // stage 64 cols of seg at a time
    const float* s = seg + ((size_t)(m * 32 + r) * NT + t) * NH + kc2 * 64 + qq * 8;
    float4 a = ((const float4*)s)[0];
    float4 b2 = ((const float4*)s)[1];
    ls[r][qq * 8 + 0] = a.x;  ls[r][qq * 8 + 1] = a.y;
    ls[r][qq * 8 + 2] = a.z;  ls[r][qq * 8 + 3] = a.w;
    ls[r][qq * 8 + 4] = b2.x; ls[r][qq * 8 + 5] = b2.y;
    ls[r][qq * 8 + 6] = b2.z; ls[r][qq * 8 + 7] = b2.w;
    __syncthreads();
    const int sub2 = tid >> 6;               // 0..3 -> (kc half, sub)
    const int kc = kc2 * 2 + (sub2 >> 1);
    const int sub = sub2 & 1;
    const int row = sub * 16 + (l & 15);
    const int c0 = (sub2 >> 1) * 32 + (l >> 4) * 8;
    u16 o[8];
#pragma unroll
    for (int e = 0; e < 8; ++e) o[e] = f2h(ls[row][c0 + e]);
    ((uint4*)outb)[(kc * 2 + sub) * 64 + l] = pack8h(o);
    __syncthreads();
  }
  if (tid < 32)
    lbl[tid] = (t == 0) ? NL : labels[(size_t)(m * 32 + tid) * NT + (t - 1)];
  __syncthreads();
#pragma unroll
  for (int k = 0; k < 2; ++k) {
    int u = tid + k * 256;                   // 512 units: kc 32..35, sub, l
    int kc = 32 + (u >> 7);
    int sub = (u >> 6) & 1;
    int ll = u & 63;
    int row = sub * 16 + (ll & 15);
    int c = (kc - 32) * 32 + (ll >> 4) * 8;
    const float* s = emb + (size_t)lbl[row] * NE + c;
    float4 a = ((const float4*)s)[0];
    float4 b2 = ((const float4*)s)[1];
    u16 o[8];
    o[0] = f2h(a.x); o[1] = f2h(a.y); o[2] = f2h(a.z); o[3] = f2h(a.w);
    o[4] = f2h(b2.x); o[5] = f2h(b2.y); o[6] = f2h(b2.z); o[7] = f2h(b2.w);
    ((uint4*)outb)[(kc * 2 + sub) * 64 + ll] = pack8h(o);
  }
}

// ---------------- persistent GRU kernel ----------------
#define MFMA16(a, b, c) __builtin_amdgcn_mfma_f32_16x16x32_f16((a), (b), (c), 0, 0, 0)

// stage group h tile (parity p_) from hbuf into hlds via LDS-DMA; barrier after
#define STAGE_H(p_) do { \
  const char* gb_ = (const char*)hbuf + ((size_t)((p_) * MT + m) * HB_U64_PER) * 8; \
  _Pragma("unroll") \
  for (int k_ = 0; k_ < 16; ++k_) { \
    gll16(gb_ + ((size_t)(k_ * 256 + tid)) * 16, \
          (void*)(hlds + (k_ * 256 + w * 64))); \
  } \
  asm volatile("s_waitcnt vmcnt(0)" ::: "memory"); \
  __syncthreads(); \
} while (0)

__global__ __launch_bounds__(THREADS, 1)
void gru_persist(const u16* __restrict__ xpack, const u16* __restrict__ wpack,
                 const u16* __restrict__ wopack,
                 const float* __restrict__ bih, const float* __restrict__ bhh,
                 const float* __restrict__ bout,
                 u64* __restrict__ hbuf, u32* __restrict__ counters,
                 float* __restrict__ out) {
  __shared__ uint4 hlds[HKC * 2 * 64];           // 64KB: h(t) tile, fragment-linear
  __shared__ float glds[4][2][2][4][64];         // 16KB: gate tiles / logits exchange
  __shared__ u16 hbf[32 * 40];                   // 2.5KB fp16 bounce for h write

  const int bid = blockIdx.x;
  const int xcd = bid & 7;
  const int q = bid >> 3;                    // 0..31
  const int m = q & 7;                       // group (32 rows)
  const int jslot = q >> 3;                  // 0..3
  const int jt = jslot * 8 + xcd;            // 4 distinct jt per XCD -> weights L2-resident
  const int tid = threadIdx.x;
  const int w = tid >> 6, l = tid & 63;
  const int l15 = l & 15, l4 = l >> 4;
  const int usub = w >> 1, uni = w & 1;      // this thread's update subtile (fixed)

  const uint4* xp = (const uint4*)xpack;
  const uint4* wp = (const uint4*)wpack;
  const uint4* wo = (const uint4*)wopack;
  f32x4* redv4 = (f32x4*)&glds[0][0][0][0][0];   // logits exchange aliasing glds
  u32* cnt = counters + m * 16;
  const size_t wbase_u = (size_t)jt * (KCT * 6 * 64);

  // biases for this thread's update columns (zero here, honored anyway)
  const int ocol = jt * 32 + uni * 16 + l15;
  const float br = bih[ocol] + bhh[ocol];
  const float bz = bih[NH + ocol] + bhh[NH + ocol];
  const float bxn = bih[2 * NH + ocol];
  const float bhn = bhh[2 * NH + ocol];
  float hold[4] = {0.f, 0.f, 0.f, 0.f};
  const f32x4 z4 = {0.f, 0.f, 0.f, 0.f};

  for (int t = 0; t < NT; ++t) {
    const int par = t & 1;
    const size_t xbase_u = (size_t)(m * NT + t) * (XKC * 2 * 64);
    const bool duty = (jt == (t & 31));

    // gate accumulator for this wave: w0=R, w1=Z, w2=XN, w3=HN
    f32x4 acc[2][2];
    acc[0][0] = z4; acc[0][1] = z4; acc[1][0] = z4; acc[1][1] = z4;

    // ---- x phase: waves 0..2 accumulate gate w's x-part ----
    if (w < 3) {
      const int g = w;
#pragma unroll 4
      for (int kc = 0; kc < XKC; ++kc) {
        uint4 A0 = xp[xbase_u + (size_t)(kc * 2 + 0) * 64 + l];
        uint4 A1 = xp[xbase_u + (size_t)(kc * 2 + 1) * 64 + l];
        uint4 B0 = wp[wbase_u + (size_t)((kc * 3 + g) * 2 + 0) * 64 + l];
        uint4 B1 = wp[wbase_u + (size_t)((kc * 3 + g) * 2 + 1) * 64 + l];
        half8 a0 = __builtin_bit_cast(half8, A0);
        half8 a1 = __builtin_bit_cast(half8, A1);
        half8 b0 = __builtin_bit_cast(half8, B0);
        half8 b1 = __builtin_bit_cast(half8, B1);
        acc[0][0] = MFMA16(a0, b0, acc[0][0]);
        acc[0][1] = MFMA16(a0, b1, acc[0][1]);
        acc[1][0] = MFMA16(a1, b0, acc[1][0]);
        acc[1][1] = MFMA16(a1, b1, acc[1][1]);
      }
    }

    // ---- wait for group's h(t): relaxed spin ----
    if (tid == 0) {
      const u32 target = 32u * (u32)t;
      while (__hip_atomic_load(cnt, __ATOMIC_RELAXED, __HIP_MEMORY_SCOPE_AGENT) < target)
        __builtin_amdgcn_s_sleep(1);
    }
    __syncthreads();

    // ---- stage h(t) into LDS (DMA, zero registers) ----
    STAGE_H(par);

    // ---- h phase: waves 0,1,3 accumulate gate's h-part (R,Z sums add in) ----
    if (w != 2) {
      const int g = (w == 3) ? 2 : w;
#pragma unroll 4
      for (int kc = 0; kc < HKC; ++kc) {
        uint4 A0 = hlds[(kc * 2 + 0) * 64 + l];
        uint4 A1 = hlds[(kc * 2 + 1) * 64 + l];
        uint4 B0 = wp[wbase_u + (size_t)(((XKC + kc) * 3 + g) * 2 + 0) * 64 + l];
        uint4 B1 = wp[wbase_u + (size_t)(((XKC + kc) * 3 + g) * 2 + 1) * 64 + l];
        half8 a0 = __builtin_bit_cast(half8, A0);
        half8 a1 = __builtin_bit_cast(half8, A1);
        half8 b0 = __builtin_bit_cast(half8, B0);
        half8 b1 = __builtin_bit_cast(half8, B1);
        acc[0][0] = MFMA16(a0, b0, acc[0][0]);
        acc[0][1] = MFMA16(a0, b1, acc[0][1]);
        acc[1][0] = MFMA16(a1, b0, acc[1][0]);
        acc[1][1] = MFMA16(a1, b1, acc[1][1]);
      }
    }

    // ---- publish gate tiles (wave w -> glds[w]) ----
#pragma unroll
    for (int s = 0; s < 2; ++s)
#pragma unroll
      for (int n = 0; n < 2; ++n)
#pragma unroll
        for (int rg = 0; rg < 4; ++rg)
          glds[w][s][n][rg][l] = acc[s][n][rg];
    __syncthreads();

    // ---- gate math: thread (usub,uni,l) updates its 4 elements ----
#pragma unroll
    for (int rg = 0; rg < 4; ++rg) {
      float R   = glds[0][usub][uni][rg][l] + br;
      float Z   = glds[1][usub][uni][rg][l] + bz;
      float XNv = glds[2][usub][uni][rg][l] + bxn;
      float HNv = glds[3][usub][uni][rg][l] + bhn;
      float r_ = 1.f / (1.f + __expf(-R));
      float z_ = 1.f / (1.f + __expf(-Z));
      float pre = XNv + r_ * HNv;
      float e2 = __expf(2.f * pre);
      float n_ = 1.f - 2.f / (e2 + 1.f);
      float hn_ = (1.f - z_) * n_ + z_ * hold[rg];
      hold[rg] = hn_;
      hbf[(usub * 16 + l4 * 4 + rg) * 40 + uni * 16 + l15] = f2h(hn_);
    }
    __syncthreads();

    // ---- write h(t+1) chunk kc=jt (waves 0,1 = sub 0,1) ----
    if (w < 2) {
      const int row = w * 16 + l15;
      const uint4 hv = *(const uint4*)&hbf[(size_t)row * 40 + l4 * 8];
      u64 lo = ((u64)hv.y << 32) | (u64)hv.x;
      u64 hi = ((u64)hv.w << 32) | (u64)hv.z;
      u64* dst = hbuf + (size_t)((par ^ 1) * MT + m) * HB_U64_PER
                      + ((size_t)(jt * 2 + w) * 64 + l) * 2;
      __hip_atomic_store(dst, lo, __ATOMIC_RELAXED, __HIP_MEMORY_SCOPE_AGENT);
      __hip_atomic_store(dst + 1, hi, __ATOMIC_RELAXED, __HIP_MEMORY_SCOPE_AGENT);
    }
    __syncthreads();   // drains stores; also closes glds read/write epoch
    if (tid == 0)
      __hip_atomic_fetch_add(cnt, 1u, __ATOMIC_RELEASE, __HIP_MEMORY_SCOPE_AGENT);

    // ---- rotating duty block: logits[:, t-1] from LDS h(t) (post-signal) ----
    if (duty && t > 0) {
      f32x4 aL[2][2];
      aL[0][0] = z4; aL[0][1] = z4; aL[1][0] = z4; aL[1][1] = z4;
#pragma unroll
      for (int c_ = 0; c_ < 8; ++c_) {
        const int kc_ = w * 8 + c_;
        uint4 A0 = hlds[(kc_ * 2 + 0) * 64 + l];
        uint4 A1 = hlds[(kc_ * 2 + 1) * 64 + l];
        uint4 O0 = wo[(size_t)(kc_ * 2 + 0) * 64 + l];
        uint4 O1 = wo[(size_t)(kc_ * 2 + 1) * 64 + l];
        half8 a0 = __builtin_bit_cast(half8, A0);
        half8 a1 = __builtin_bit_cast(half8, A1);
        half8 o0 = __builtin_bit_cast(half8, O0);
        half8 o1 = __builtin_bit_cast(half8, O1);
        aL[0][0] = MFMA16(a0, o0, aL[0][0]);
        aL[0][1] = MFMA16(a0, o1, aL[0][1]);
        aL[1][0] = MFMA16(a1, o0, aL[1][0]);
        aL[1][1] = MFMA16(a1, o1, aL[1][1]);
      }
      f32x4 sL;
#pragma unroll
      for (int o = 0; o < 4; ++o) {
        if (o == w) sL = aL[usub][uni];
        else {
          const int slot = (w > o) ? (w - 1) : w;
          redv4[(o * 3 + slot) * 64 + l] = aL[o >> 1][o & 1];
        }
      }
      __syncthreads();
#pragma unroll
      for (int slot = 0; slot < 3; ++slot)
        sL += redv4[(w * 3 + slot) * 64 + l];
      const int col = uni * 16 + l15;
      if (col < NL) {
#pragma unroll
        for (int rg = 0; rg < 4; ++rg) {
          const int row = usub * 16 + l4 * 4 + rg;
          const size_t b_ = (size_t)m * 32 + row;
          out[(b_ * NT + (t - 1)) * NL + col] = sL[rg] + bout[col];
        }
      }
      __syncthreads();
    }
  }

  // ---- epilogue: logits[:, 511] from h_512 (parity 0), blocks jt==0 ----
  if (jt == 0) {
    if (tid == 0) {
      while (__hip_atomic_load(cnt, __ATOMIC_RELAXED, __HIP_MEMORY_SCOPE_AGENT) < 32u * 512u)
        __builtin_amdgcn_s_sleep(1);
    }
    __syncthreads();
    STAGE_H(0);
    f32x4 aL[2][2];
    const f32x4 z4b = {0.f, 0.f, 0.f, 0.f};
    aL[0][0] = z4b; aL[0][1] = z4b; aL[1][0] = z4b; aL[1][1] = z4b;
#pragma unroll
    for (int c_ = 0; c_ < 8; ++c_) {
      const int kc_ = w * 8 + c_;
      uint4 A0 = hlds[(kc_ * 2 + 0) * 64 + l];
      uint4 A1 = hlds[(kc_ * 2 + 1) * 64 + l];
      uint4 O0 = wo[(size_t)(kc_ * 2 + 0) * 64 + l];
      uint4 O1 = wo[(size_t)(kc_ * 2 + 1) * 64 + l];
      half8 a0 = __builtin_bit_cast(half8, A0);
      half8 a1 = __builtin_bit_cast(half8, A1);
      half8 o0 = __builtin_bit_cast(half8, O0);
      half8 o1 = __builtin_bit_cast(half8, O1);
      aL[0][0] = MFMA16(a0, o0, aL[0][0]);
      aL[0][1] = MFMA16(a0, o1, aL[0][1]);
      aL[1][0] = MFMA16(a1, o0, aL[1][0]);
      aL[1][1] = MFMA16(a1, o1, aL[1][1]);
    }
    f32x4 sL;
#pragma unroll
    for (int o = 0; o < 4; ++o) {
      if (o == w) sL = aL[usub][uni];
      else {
        const int slot = (w > o) ? (w - 1) : w;
        redv4[(o * 3 + slot) * 64 + l] = aL[o >> 1][o & 1];
      }
    }
    __syncthreads();
#pragma unroll
    for (int slot = 0; slot < 3; ++slot)
      sL += redv4[(w * 3 + slot) * 64 + l];
    const int col = uni * 16 + l15;
    if (col < NL) {
#pragma unroll
      for (int rg = 0; rg < 4; ++rg) {
        const int row = usub * 16 + l4 * 4 + rg;
        const size_t b_ = (size_t)m * 32 + row;
        out[(b_ * NT + 511) * NL + col] = sL[rg] + bout[col];
      }
    }
  }
}

extern "C" void kernel_launch(void* const* d_in, const int* in_sizes, int n_in,
                              void* d_out, int out_size, void* d_ws, size_t ws_size,
                              hipStream_t stream) {
  (void)in_sizes; (void)n_in; (void)out_size;
  const float* seg   = (const float*)d_in[0];
  const int*   labels= (const int*)d_in[1];
  const float* emb   = (const float*)d_in[2];
  const float* Wih   = (const float*)d_in[3];
  const float* Whh   = (const float*)d_in[4];
  const float* bih   = (const float*)d_in[5];
  const float* bhh   = (const float*)d_in[6];
  const float* Wout  = (const float*)d_in[7];
  const float* bout  = (const float*)d_in[8];
  float* out = (float*)d_out;
  char* ws = (char*)d_ws;
  if (ws_size < WS_TOTAL) return;

  zero_ws<<<129, 256, 0, stream>>>((uint4*)(ws + WS_CNT));
  pack_w<<<3280, 256, 0, stream>>>(Wih, Whh, Wout,
                                   (u16*)(ws + WS_WPACK), (u16*)(ws + WS_WOPACK));
  pack_x<<<4096, 256, 0, stream>>>(seg, labels, emb, (u16*)(ws + WS_XPACK));
  gru_persist<<<NBLK, THREADS, 0, stream>>>(
      (const u16*)(ws + WS_XPACK), (const u16*)(ws + WS_WPACK),
      (const u16*)(ws + WS_WOPACK), bih, bhh, bout,
      (u64*)(ws + WS_HBUF), (u32*)(ws + WS_CNT), out);
}